// Round 1
// baseline (2167.732 us; speedup 1.0000x reference)
//
#include <hip/hip_runtime.h>
#include <math.h>

// Problem constants
#define SLEN 1024
#define NH 8
#define DH 64
#define HDIM 512
#define BATCH 16
#define NROWS (BATCH * SLEN)          // 16384
#define BHN (BATCH * NH)              // 128
#define BHROWS (BHN * SLEN)           // 131072

// Workspace layout (float offsets). Total 50,593,792 floats = 202.4 MB.
// Lifetimes: qcat/kcat live until score_gemm; vcat until pv; ctx (aliases kcat)
// written by pv, read by gemm<1>; tmp (aliases qcat) written by gemm<1>, read by ln.
#define QCAT_OFF 0LL
#define KCAT_OFF 16777216LL
#define VCAT_OFF 33554432LL
#define SUM_OFF  50331648LL           // qsum[131072] then ksum[131072]
#define CTXM_OFF KCAT_OFF
#define CTXC_OFF (KCAT_OFF + 8388608LL)
#define TMP0_OFF QCAT_OFF
#define TMP1_OFF (QCAT_OFF + 8388608LL)

struct Args {
    const float *xm, *xrm, *xc, *xrc;
    const float *w[8];     // mq,mk,mv,cq,ck,cv,md,cd
    const float *bias[8];
    const float *ln_w, *ln_b;
    float *ws;
    float *out_m, *out_c, *probs;
};

// ---------------------------------------------------------------------------
// GEMM: C[16384,512] = A[16384,512] @ W[512,512] (+bias, +act, +resid)
// MODE 0: 6 projections -> head-split concatenated layout [B,NH,S,128]
// MODE 1: 2 output GEMMs -> plain [16384,512] with residual add
// 128x128 tile, BK=8, 256 threads, 8x8 micro-tile.
// ---------------------------------------------------------------------------
template <int MODE>
__global__ void __launch_bounds__(256) gemm_k(Args P) {
    const int op = blockIdx.z;
    const float *A, *W, *bias;
    const float *resid = nullptr;
    float *dst = nullptr;
    int doff = 0, act = 0;
    if (MODE == 0) {
        switch (op) {
            case 0: A = P.xm;  W = P.w[0]; bias = P.bias[0]; dst = P.ws + QCAT_OFF; doff = 0;  act = 0; break;
            case 1: A = P.xm;  W = P.w[1]; bias = P.bias[1]; dst = P.ws + KCAT_OFF; doff = 0;  act = 0; break;
            case 2: A = P.xrm; W = P.w[2]; bias = P.bias[2]; dst = P.ws + VCAT_OFF; doff = 0;  act = 0; break;
            case 3: A = P.xc;  W = P.w[3]; bias = P.bias[3]; dst = P.ws + QCAT_OFF; doff = DH; act = 1; break;
            case 4: A = P.xc;  W = P.w[4]; bias = P.bias[4]; dst = P.ws + KCAT_OFF; doff = DH; act = 1; break;
            default:A = P.xrc; W = P.w[5]; bias = P.bias[5]; dst = P.ws + VCAT_OFF; doff = DH; act = 2; break;
        }
    } else {
        if (op == 0) { A = P.ws + CTXM_OFF; W = P.w[6]; bias = P.bias[6]; resid = P.xm; dst = P.ws + TMP0_OFF; }
        else         { A = P.ws + CTXC_OFF; W = P.w[7]; bias = P.bias[7]; resid = P.xc; dst = P.ws + TMP1_OFF; }
    }

    __shared__ float As[8][128];   // k-major
    __shared__ float Bs[8][128];
    const int t = threadIdx.x;
    const int m0 = blockIdx.y * 128, n0 = blockIdx.x * 128;
    const int tx = t & 15, ty = t >> 4;
    const int arow = t >> 1, acol = (t & 1) * 4;   // A tile: 128 rows x 8 k
    const int brow = t >> 5, bcol = (t & 31) * 4;  // B tile: 8 k x 128 cols

    float acc[8][8];
#pragma unroll
    for (int i = 0; i < 8; ++i)
#pragma unroll
        for (int j = 0; j < 8; ++j) acc[i][j] = 0.f;

    const float *Aptr = A + (size_t)(m0 + arow) * HDIM + acol;
    const float *Wptr = W + (size_t)brow * HDIM + n0 + bcol;

    for (int k0 = 0; k0 < HDIM; k0 += 8) {
        float4 av = *(const float4 *)(Aptr + k0);
        float4 bv = *(const float4 *)(Wptr + (size_t)k0 * HDIM);
        __syncthreads();
        As[acol + 0][arow] = av.x; As[acol + 1][arow] = av.y;
        As[acol + 2][arow] = av.z; As[acol + 3][arow] = av.w;
        *(float4 *)&Bs[brow][bcol] = bv;
        __syncthreads();
#pragma unroll
        for (int kk = 0; kk < 8; ++kk) {
            float a[8], bb[8];
#pragma unroll
            for (int i = 0; i < 8; ++i) a[i] = As[kk][ty * 8 + i];
#pragma unroll
            for (int j = 0; j < 8; ++j) bb[j] = Bs[kk][tx * 8 + j];
#pragma unroll
            for (int i = 0; i < 8; ++i)
#pragma unroll
                for (int j = 0; j < 8; ++j)
                    acc[i][j] = fmaf(a[i], bb[j], acc[i][j]);
        }
    }

#pragma unroll
    for (int i = 0; i < 8; ++i) {
        const int r = m0 + ty * 8 + i;
#pragma unroll
        for (int j = 0; j < 8; ++j) {
            const int c = n0 + tx * 8 + j;
            float v = acc[i][j] + bias[c];
            if (MODE == 0) {
                if (act == 1) {            // sqrt(clip(elu(x)+1, 1e-24))
                    float e = v > 0.f ? v + 1.f : expf(v);
                    e = fmaxf(e, 1e-24f);
                    v = sqrtf(e);
                } else if (act == 2) {     // elu(x)+1
                    v = v > 0.f ? v + 1.f : expf(v);
                }
                const int b_ = r >> 10, s_ = r & (SLEN - 1);
                const int h_ = c >> 6, d_ = c & (DH - 1);
                dst[((size_t)(b_ * NH + h_) * SLEN + s_) * 128 + doff + d_] = v;
            } else {
                v += resid[(size_t)r * HDIM + c];
                dst[(size_t)r * HDIM + c] = v;
            }
        }
    }
}

// ---------------------------------------------------------------------------
// Row sums: qsum = sum(qcat^2) over 128 (= sum mq^2 + sum cq), ksum likewise.
// One wave per row.
// ---------------------------------------------------------------------------
__global__ void __launch_bounds__(256) rowsum_k(const float *ws, float *sums) {
    const int t = threadIdx.x;
    const int wv = t >> 6, lane = t & 63;
    const long long row = (long long)blockIdx.x * 4 + wv;   // 0..262143
    const float *src = (row < BHROWS) ? (ws + QCAT_OFF) : (ws + KCAT_OFF);
    const long long r = row & (BHROWS - 1);
    const float *p = src + r * 128;
    float a = p[lane], b = p[64 + lane];
    float v = a * a + b * b;
#pragma unroll
    for (int o = 32; o > 0; o >>= 1) v += __shfl_xor(v, o);
    if (lane == 0) sums[row] = v;
}

// ---------------------------------------------------------------------------
// Scores GEMM: per (b,h): raw[i][j] = (2*dot128(q_i,k_j) - qsum_i - ksum_j)/8,
// masked (j>i) -> -1e30 sentinel. Written into the probs output region.
// Upper-triangle 128x128 blocks skipped entirely (softmax never reads them).
// ---------------------------------------------------------------------------
__global__ void __launch_bounds__(256) score_gemm(const float *ws, float *probs) {
    const int bh = blockIdx.z;
    const int m0 = blockIdx.y * 128;   // query tile
    const int n0 = blockIdx.x * 128;   // key tile
    if (n0 > m0) return;               // fully masked block

    const float *qc = ws + QCAT_OFF + (size_t)bh * SLEN * 128;
    const float *kc = ws + KCAT_OFF + (size_t)bh * SLEN * 128;
    const float *qsum = ws + SUM_OFF + (size_t)bh * SLEN;
    const float *ksum = ws + SUM_OFF + BHROWS + (size_t)bh * SLEN;

    __shared__ float As[8][128];
    __shared__ float Bs[8][128];
    const int t = threadIdx.x;
    const int tx = t & 15, ty = t >> 4;
    const int lrow = t >> 1, lcol = (t & 1) * 4;

    float acc[8][8];
#pragma unroll
    for (int i = 0; i < 8; ++i)
#pragma unroll
        for (int j = 0; j < 8; ++j) acc[i][j] = 0.f;

    const float *Aptr = qc + (size_t)(m0 + lrow) * 128 + lcol;
    const float *Bptr = kc + (size_t)(n0 + lrow) * 128 + lcol;

    for (int k0 = 0; k0 < 128; k0 += 8) {
        float4 av = *(const float4 *)(Aptr + k0);
        float4 bv = *(const float4 *)(Bptr + k0);
        __syncthreads();
        As[lcol + 0][lrow] = av.x; As[lcol + 1][lrow] = av.y;
        As[lcol + 2][lrow] = av.z; As[lcol + 3][lrow] = av.w;
        Bs[lcol + 0][lrow] = bv.x; Bs[lcol + 1][lrow] = bv.y;
        Bs[lcol + 2][lrow] = bv.z; Bs[lcol + 3][lrow] = bv.w;
        __syncthreads();
#pragma unroll
        for (int kk = 0; kk < 8; ++kk) {
            float a[8], bb[8];
#pragma unroll
            for (int i = 0; i < 8; ++i) a[i] = As[kk][ty * 8 + i];
#pragma unroll
            for (int j = 0; j < 8; ++j) bb[j] = Bs[kk][tx * 8 + j];
#pragma unroll
            for (int i = 0; i < 8; ++i)
#pragma unroll
                for (int j = 0; j < 8; ++j)
                    acc[i][j] = fmaf(a[i], bb[j], acc[i][j]);
        }
    }

    float qs[8], ks2[8];
#pragma unroll
    for (int i = 0; i < 8; ++i) qs[i] = qsum[m0 + ty * 8 + i];
#pragma unroll
    for (int j = 0; j < 8; ++j) ks2[j] = ksum[n0 + tx * 8 + j];

#pragma unroll
    for (int i = 0; i < 8; ++i) {
        const int gi = m0 + ty * 8 + i;
        float o[8];
#pragma unroll
        for (int j = 0; j < 8; ++j) {
            const int gj = n0 + tx * 8 + j;
            float sv = (2.f * acc[i][j] - qs[i] - ks2[j]) * 0.125f;
            o[j] = (gj > gi) ? -1e30f : sv;
        }
        float *prow = probs + ((size_t)bh * SLEN + gi) * SLEN + n0 + tx * 8;
        *(float4 *)prow = make_float4(o[0], o[1], o[2], o[3]);
        *(float4 *)(prow + 4) = make_float4(o[4], o[5], o[6], o[7]);
    }
}

// ---------------------------------------------------------------------------
// In-place row softmax over the probs buffer. One 256-thread block per row.
// Reads only the computed region [0, kend); writes the full row (exact zeros
// in the masked tail and for global query row 0).
// ---------------------------------------------------------------------------
__global__ void __launch_bounds__(256) softmax_k(float *probs) {
    const long long row = blockIdx.x;          // 0..131071
    const int i = (int)(row & (SLEN - 1));     // s index
    float *p = probs + row * SLEN;
    const int kend = (i & ~127) + 128;
    const int t = threadIdx.x;
    const bool activ = (t * 4) < kend;

    float4 v = make_float4(-1e30f, -1e30f, -1e30f, -1e30f);
    if (activ) v = ((const float4 *)p)[t];

    float m = fmaxf(fmaxf(v.x, v.y), fmaxf(v.z, v.w));
    __shared__ float smax[4];
    __shared__ float ssum[4];
    const int wv = t >> 6, lane = t & 63;
#pragma unroll
    for (int o = 32; o > 0; o >>= 1) m = fmaxf(m, __shfl_xor(m, o));
    if (lane == 0) smax[wv] = m;
    __syncthreads();
    m = fmaxf(fmaxf(smax[0], smax[1]), fmaxf(smax[2], smax[3]));

    float e0 = 0.f, e1 = 0.f, e2 = 0.f, e3 = 0.f;
    if (activ) {
        e0 = expf(v.x - m); e1 = expf(v.y - m);
        e2 = expf(v.z - m); e3 = expf(v.w - m);
    }
    float s = e0 + e1 + e2 + e3;
#pragma unroll
    for (int o = 32; o > 0; o >>= 1) s += __shfl_xor(s, o);
    if (lane == 0) ssum[wv] = s;
    __syncthreads();
    const float total = ssum[0] + ssum[1] + ssum[2] + ssum[3];

    const float scale = (i == 0) ? 0.f : (1.f / total);  // zero_pad row 0
    ((float4 *)p)[t] = make_float4(e0 * scale, e1 * scale, e2 * scale, e3 * scale);
}

// ---------------------------------------------------------------------------
// PV: ctx_m = probs @ mv, ctx_c = probs^2 @ cv. Block = (b, h, 64-row q tile).
// Causal: only k-chunks <= q0 are touched (rest of probs is exactly 0).
// Output written merged-heads [B,S,H] into ctx buffers.
// ---------------------------------------------------------------------------
__global__ void __launch_bounds__(256) pv_k(const float *probs, float *ws) {
    __shared__ float ps[64][65];
    __shared__ float vs[64][132];
    const int qt = blockIdx.x, h = blockIdx.y, b = blockIdx.z;
    const int bh = b * NH + h, q0 = qt * 64;
    const int t = threadIdx.x;
    const int rg = t >> 4, cg = t & 15;

    float am[4][4], ac[4][4];
#pragma unroll
    for (int r = 0; r < 4; ++r)
#pragma unroll
        for (int u = 0; u < 4; ++u) { am[r][u] = 0.f; ac[r][u] = 0.f; }

    const int nch = (q0 >> 6) + 1;
    const float *vc = ws + VCAT_OFF + (size_t)bh * SLEN * 128;
    const float *pb = probs + (size_t)bh * SLEN * SLEN;

    for (int c = 0; c < nch; ++c) {
        const int k0 = c * 64;
        __syncthreads();
#pragma unroll
        for (int it = 0; it < 4; ++it) {
            const int idx = it * 256 + t;
            const int r = idx >> 4, c4 = (idx & 15) * 4;
            float4 v = *(const float4 *)(pb + (size_t)(q0 + r) * SLEN + k0 + c4);
            ps[r][c4 + 0] = v.x; ps[r][c4 + 1] = v.y;
            ps[r][c4 + 2] = v.z; ps[r][c4 + 3] = v.w;
        }
#pragma unroll
        for (int it = 0; it < 8; ++it) {
            const int idx = it * 256 + t;
            const int r = idx >> 5, c4 = (idx & 31) * 4;
            float4 v = *(const float4 *)(vc + (size_t)(k0 + r) * 128 + c4);
            *(float4 *)&vs[r][c4] = v;
        }
        __syncthreads();
#pragma unroll 4
        for (int kk = 0; kk < 64; ++kk) {
            float a[4], a2[4], bm[4], bc[4];
#pragma unroll
            for (int r = 0; r < 4; ++r) { a[r] = ps[rg * 4 + r][kk]; a2[r] = a[r] * a[r]; }
#pragma unroll
            for (int u = 0; u < 4; ++u) { bm[u] = vs[kk][cg * 4 + u]; bc[u] = vs[kk][64 + cg * 4 + u]; }
#pragma unroll
            for (int r = 0; r < 4; ++r)
#pragma unroll
                for (int u = 0; u < 4; ++u) {
                    am[r][u] = fmaf(a[r], bm[u], am[r][u]);
                    ac[r][u] = fmaf(a2[r], bc[u], ac[r][u]);
                }
        }
    }

    float *ctxm = ws + CTXM_OFF;
    float *ctxc = ws + CTXC_OFF;
#pragma unroll
    for (int r = 0; r < 4; ++r) {
        const size_t row = (size_t)b * SLEN + q0 + rg * 4 + r;
#pragma unroll
        for (int u = 0; u < 4; ++u) {
            const int col = h * DH + cg * 4 + u;
            ctxm[row * HDIM + col] = am[r][u];
            ctxc[row * HDIM + col] = ac[r][u];
        }
    }
}

// ---------------------------------------------------------------------------
// LayerNorm: one wave per row of tmp0/tmp1 -> out_m/out_c.
// ---------------------------------------------------------------------------
__global__ void __launch_bounds__(256) ln_k(const float *ws, const float *ln_w,
                                            const float *ln_b, float *out_m, float *out_c) {
    const int t = threadIdx.x;
    const int wv = t >> 6, lane = t & 63;
    const long long rid = (long long)blockIdx.x * 4 + wv;   // 0..32767
    const float *src = ws + ((rid < NROWS) ? TMP0_OFF : TMP1_OFF);
    float *dst = (rid < NROWS) ? out_m : out_c;
    const long long r = rid & (NROWS - 1);
    const float *p = src + r * HDIM;

    float4 v1 = ((const float4 *)p)[lane * 2];
    float4 v2 = ((const float4 *)p)[lane * 2 + 1];
    float s = v1.x + v1.y + v1.z + v1.w + v2.x + v2.y + v2.z + v2.w;
    float ss = v1.x * v1.x + v1.y * v1.y + v1.z * v1.z + v1.w * v1.w
             + v2.x * v2.x + v2.y * v2.y + v2.z * v2.z + v2.w * v2.w;
#pragma unroll
    for (int o = 32; o > 0; o >>= 1) { s += __shfl_xor(s, o); ss += __shfl_xor(ss, o); }

    const float mean = s * (1.f / 512.f);
    const float var = ss * (1.f / 512.f) - mean * mean;
    const float inv = 1.f / sqrtf(var + 1e-12f);
    const int c0 = lane * 8;

    float x[8] = {v1.x, v1.y, v1.z, v1.w, v2.x, v2.y, v2.z, v2.w};
    float o[8];
#pragma unroll
    for (int e = 0; e < 8; ++e)
        o[e] = ln_w[c0 + e] * ((x[e] - mean) * inv) + ln_b[c0 + e];
    float *q = dst + r * HDIM + c0;
    *(float4 *)q = make_float4(o[0], o[1], o[2], o[3]);
    *(float4 *)(q + 4) = make_float4(o[4], o[5], o[6], o[7]);
}

// ---------------------------------------------------------------------------
extern "C" void kernel_launch(void *const *d_in, const int *in_sizes, int n_in,
                              void *d_out, int out_size, void *d_ws, size_t ws_size,
                              hipStream_t stream) {
    (void)in_sizes; (void)n_in; (void)out_size; (void)ws_size;
    Args P;
    P.xm  = (const float *)d_in[0];
    P.xrm = (const float *)d_in[1];
    P.xc  = (const float *)d_in[2];
    P.xrc = (const float *)d_in[3];
    // d_in[4] = attn_mask: unused — it is exactly where(causal,0,-1e4) and the
    // -1e4 branch underflows to exact 0 probability; causal handling reproduces it bit-exactly.
    for (int i = 0; i < 8; ++i) {
        P.w[i]    = (const float *)d_in[5 + 2 * i];
        P.bias[i] = (const float *)d_in[6 + 2 * i];
    }
    P.ln_w = (const float *)d_in[21];
    P.ln_b = (const float *)d_in[22];
    P.ws = (float *)d_ws;
    P.out_m = (float *)d_out;
    P.out_c = (float *)d_out + 8388608;
    P.probs = (float *)d_out + 16777216;

    gemm_k<0><<<dim3(4, 128, 6), dim3(256), 0, stream>>>(P);
    rowsum_k<<<dim3(65536), dim3(256), 0, stream>>>(P.ws, P.ws + SUM_OFF);
    score_gemm<<<dim3(8, 8, 128), dim3(256), 0, stream>>>(P.ws, P.probs);
    softmax_k<<<dim3(131072), dim3(256), 0, stream>>>(P.probs);
    pv_k<<<dim3(16, 8, 16), dim3(256), 0, stream>>>(P.probs, P.ws);
    gemm_k<1><<<dim3(4, 128, 2), dim3(256), 0, stream>>>(P);
    ln_k<<<dim3(8192), dim3(256), 0, stream>>>(P.ws, P.ln_w, P.ln_b, P.out_m, P.out_c);
}

// Round 5
// 763.165 us; speedup vs baseline: 2.8404x; 2.8404x over previous
//
#include <hip/hip_runtime.h>
#include <math.h>

// Problem constants
#define SLEN 1024
#define NH 8
#define DH 64
#define HDIM 512
#define BATCH 16
#define NROWS (BATCH * SLEN)          // 16384
#define BHN (BATCH * NH)              // 128
#define BHROWS (BHN * SLEN)           // 131072

typedef short bf16x8 __attribute__((ext_vector_type(8)));
typedef unsigned short u16x8 __attribute__((ext_vector_type(8)));
typedef float f32x4 __attribute__((ext_vector_type(4)));

__device__ __forceinline__ unsigned short f2bf(float f) {
    unsigned u = __float_as_uint(f);
    u += 0x7fffu + ((u >> 16) & 1u);           // RNE
    return (unsigned short)(u >> 16);
}
__device__ __forceinline__ float bf2f(unsigned short h) {
    return __uint_as_float(((unsigned)h) << 16);
}

// ---------------------------------------------------------------------------
// Workspace layout (BYTE offsets). Peak 173,015,040 B (< round-1's 202 MB).
//   xbf      @ 0          : 4 x 16,777,216 (xm,xrm,xc,xrc bf16)   [dead after proj]
//   vcat_t   @ 0          : 33,554,432 (aliases xbf)              [written after proj]
//   wt       @ 67,108,864 : 8 x 524,288 (W^T bf16 [n][k])
//   sums     @ 71,303,168 : 1,048,576 (qsum|ksum fp32)
//   qcat     @ 72,351,744 : 33,554,432 bf16 [bh][s][128]          [dead after score]
//     ctxm   @ 72,351,744 : 16,777,216 bf16, ctxc @ 89,128,960
//   kcat     @105,906,176 : 33,554,432                            [dead after score]
//     tmp0   @105,906,176 : 33,554,432 fp32
//   vcat     @139,460,608 : 33,554,432                            [dead after vtrans]
//     tmp1   @139,460,608 : 33,554,432 fp32
// ---------------------------------------------------------------------------
struct Args {
    const float *xm, *xrm, *xc, *xrc;
    const float *w[8], *bias[8];
    const float *ln_w, *ln_b;
    unsigned short *xbf, *wt;
    float *sums;
    unsigned short *qcat, *kcat, *vcat, *vcat_t, *ctxm, *ctxc;
    float *tmp0, *tmp1;
    float *out_m, *out_c, *probs;
};

// ---------------------------------------------------------------------------
// Convert the 4 fp32 activation inputs to bf16.
// grid (4096, 4) x 256: 4096 * 256 * 8 = 8,388,608 elements per input (exact).
// (Round-3 bug: grid.x was 8192 -> 2x OOB read past d_in => GPU fault.)
// ---------------------------------------------------------------------------
__global__ void __launch_bounds__(256) cvt_inputs_k(Args P) {
    const int which = blockIdx.y;
    const float *s = which == 0 ? P.xm : which == 1 ? P.xrm : which == 2 ? P.xc : P.xrc;
    unsigned short *d = P.xbf + (size_t)which * 8388608;
    const long long i = ((long long)blockIdx.x * 256 + threadIdx.x) * 8;
    if (i >= 8388608) return;          // safety guard
    float4 a = *(const float4 *)(s + i);
    float4 b = *(const float4 *)(s + i + 4);
    u16x8 o;
    o[0] = f2bf(a.x); o[1] = f2bf(a.y); o[2] = f2bf(a.z); o[3] = f2bf(a.w);
    o[4] = f2bf(b.x); o[5] = f2bf(b.y); o[6] = f2bf(b.z); o[7] = f2bf(b.w);
    *(u16x8 *)(d + i) = o;
}

// ---------------------------------------------------------------------------
// Transpose+convert the 8 weight matrices: WT[n][k] = bf16(W[k][n]).
// grid (64 tiles, 8 mats) x 256, 64x64 tiles via LDS.
// ---------------------------------------------------------------------------
__global__ void __launch_bounds__(256) wtrans_k(Args P) {
    const int op = blockIdx.y;
    const float *W = P.w[op];
    unsigned short *WT = P.wt + (size_t)op * 262144;
    const int kt = blockIdx.x >> 3, nt = blockIdx.x & 7;
    __shared__ float Ws[64][65];
    const int t = threadIdx.x;
#pragma unroll
    for (int it = 0; it < 4; ++it) {
        int g = t + 256 * it;
        int k = g >> 4, n4 = (g & 15) * 4;
        float4 v = *(const float4 *)(W + (size_t)(kt * 64 + k) * 512 + nt * 64 + n4);
        Ws[k][n4] = v.x; Ws[k][n4 + 1] = v.y; Ws[k][n4 + 2] = v.z; Ws[k][n4 + 3] = v.w;
    }
    __syncthreads();
#pragma unroll
    for (int it = 0; it < 2; ++it) {
        int g = t + 256 * it;
        int n = g >> 3, kg = (g & 7) * 8;
        u16x8 o;
#pragma unroll
        for (int e = 0; e < 8; ++e) o[e] = f2bf(Ws[kg + e][n]);
        *(u16x8 *)(WT + (size_t)(nt * 64 + n) * 512 + kt * 64 + kg) = o;
    }
}

// ---------------------------------------------------------------------------
// bf16 MFMA GEMM, 128x128 tile, BK=64, 4 waves (2x2, 64x64 each).
// MODE 0: C = bf16act(Xbf @ WT^T + bias) -> qcat/kcat/vcat [bh][s][128]
// MODE 1: C = ctx @ WT^T + bias + resid -> tmp fp32 [16384][512]
// LDS tiles XOR-swizzled (T2): 16B group g of row r stored at g ^ (r&7).
// ---------------------------------------------------------------------------
template <int MODE>
__global__ void __launch_bounds__(256) mgemm_k(Args P) {
    const int op = blockIdx.z;
    const unsigned short *Abf, *WT;
    const float *bias;
    const float *resid = nullptr;
    unsigned short *dstb = nullptr;
    float *dstf = nullptr;
    int doff = 0, act = 0;
    if (MODE == 0) {
        const int srcidx[6] = {0, 0, 1, 2, 2, 3};
        Abf = P.xbf + (size_t)srcidx[op] * 8388608;
        WT = P.wt + (size_t)op * 262144;
        bias = P.bias[op];
        switch (op) {
            case 0: dstb = P.qcat; doff = 0;  act = 0; break;
            case 1: dstb = P.kcat; doff = 0;  act = 0; break;
            case 2: dstb = P.vcat; doff = 0;  act = 0; break;
            case 3: dstb = P.qcat; doff = 64; act = 1; break;
            case 4: dstb = P.kcat; doff = 64; act = 1; break;
            default:dstb = P.vcat; doff = 64; act = 2; break;
        }
    } else {
        Abf = (op == 0) ? P.ctxm : P.ctxc;
        WT = P.wt + (size_t)(6 + op) * 262144;
        bias = P.bias[6 + op];
        resid = (op == 0) ? P.xm : P.xc;
        dstf = (op == 0) ? P.tmp0 : P.tmp1;
    }
    const int m0 = blockIdx.y * 128, n0 = blockIdx.x * 128;

    __shared__ unsigned short As[128][64];
    __shared__ unsigned short Bs[128][64];
    const int t = threadIdx.x;
    const int wid = t >> 6, lane = t & 63;
    const int wm = wid >> 1, wn = wid & 1;
    const int l16 = lane & 15, lq = lane >> 4;

    f32x4 acc[4][4];
#pragma unroll
    for (int i = 0; i < 4; ++i)
#pragma unroll
        for (int j = 0; j < 4; ++j) acc[i][j] = (f32x4)(0.f);

    for (int k0 = 0; k0 < 512; k0 += 64) {
        __syncthreads();
#pragma unroll
        for (int it = 0; it < 4; ++it) {
            int g = t + 256 * it;
            int r = g >> 3, cg = g & 7;
            bf16x8 av = *(const bf16x8 *)(Abf + (size_t)(m0 + r) * 512 + k0 + cg * 8);
            *(bf16x8 *)&As[r][(cg ^ (r & 7)) * 8] = av;
            bf16x8 bv = *(const bf16x8 *)(WT + (size_t)(n0 + r) * 512 + k0 + cg * 8);
            *(bf16x8 *)&Bs[r][(cg ^ (r & 7)) * 8] = bv;
        }
        __syncthreads();
#pragma unroll
        for (int kk = 0; kk < 2; ++kk) {
            bf16x8 a[4], b[4];
#pragma unroll
            for (int mf = 0; mf < 4; ++mf) {
                int r = wm * 64 + mf * 16 + l16;
                int cg = kk * 4 + lq;
                a[mf] = *(const bf16x8 *)&As[r][(cg ^ (r & 7)) * 8];
            }
#pragma unroll
            for (int nf = 0; nf < 4; ++nf) {
                int r = wn * 64 + nf * 16 + l16;
                int cg = kk * 4 + lq;
                b[nf] = *(const bf16x8 *)&Bs[r][(cg ^ (r & 7)) * 8];
            }
#pragma unroll
            for (int mf = 0; mf < 4; ++mf)
#pragma unroll
                for (int nf = 0; nf < 4; ++nf)
                    acc[mf][nf] = __builtin_amdgcn_mfma_f32_16x16x32_bf16(a[mf], b[nf], acc[mf][nf], 0, 0, 0);
        }
    }

#pragma unroll
    for (int mf = 0; mf < 4; ++mf) {
#pragma unroll
        for (int nf = 0; nf < 4; ++nf) {
#pragma unroll
            for (int r = 0; r < 4; ++r) {
                const int i = m0 + wm * 64 + mf * 16 + lq * 4 + r;
                const int j = n0 + wn * 64 + nf * 16 + l16;
                float v = acc[mf][nf][r] + bias[j];
                if (MODE == 0) {
                    if (act == 1) {
                        float e = v > 0.f ? v + 1.f : expf(v);
                        v = sqrtf(fmaxf(e, 1e-24f));
                    } else if (act == 2) {
                        v = v > 0.f ? v + 1.f : expf(v);
                    }
                    const int b_ = i >> 10, s_ = i & (SLEN - 1);
                    const int h_ = j >> 6, d_ = j & (DH - 1);
                    dstb[((size_t)(b_ * NH + h_) * SLEN + s_) * 128 + doff + d_] = f2bf(v);
                } else {
                    v += resid[(size_t)i * HDIM + j];
                    dstf[(size_t)i * HDIM + j] = v;
                }
            }
        }
    }
}

// ---------------------------------------------------------------------------
// Transpose vcat [bh][s][128] -> vcat_t [bh][d][1024]. grid (8, 128) x 256.
// ---------------------------------------------------------------------------
__global__ void __launch_bounds__(256) vtrans_k(Args P) {
    const int bh = blockIdx.y;
    const int s0 = blockIdx.x * 128;
    __shared__ unsigned short Ts[128][136];
    const unsigned short *src = P.vcat + (size_t)bh * SLEN * 128;
    unsigned short *dst = P.vcat_t + (size_t)bh * 128 * SLEN;
    const int t = threadIdx.x;
#pragma unroll
    for (int it = 0; it < 8; ++it) {
        int g = t + 256 * it;
        int s = g >> 4, dg = g & 15;
        *(u16x8 *)&Ts[s][dg * 8] = *(const u16x8 *)(src + (size_t)(s0 + s) * 128 + dg * 8);
    }
    __syncthreads();
#pragma unroll
    for (int it = 0; it < 8; ++it) {
        int g = t + 256 * it;
        int d = g >> 4, sg = g & 15;
        u16x8 o;
#pragma unroll
        for (int e = 0; e < 8; ++e) o[e] = Ts[sg * 8 + e][d];
        *(u16x8 *)(dst + (size_t)d * SLEN + s0 + sg * 8) = o;
    }
}

// ---------------------------------------------------------------------------
// Row sums from bf16 qcat/kcat (consistent with MFMA operand values).
// ---------------------------------------------------------------------------
__global__ void __launch_bounds__(256) rowsum_k(Args P) {
    const int t = threadIdx.x;
    const int wv = t >> 6, lane = t & 63;
    const long long row = (long long)blockIdx.x * 4 + wv;    // 0..262143
    const unsigned short *src = (row < BHROWS) ? P.qcat : P.kcat;
    const long long r = row & (BHROWS - 1);
    const unsigned short *p = src + r * 128;
    float a = bf2f(p[lane]), b = bf2f(p[64 + lane]);
    float v = a * a + b * b;
#pragma unroll
    for (int o = 32; o > 0; o >>= 1) v += __shfl_xor(v, o);
    if (lane == 0) P.sums[row] = v;
}

// ---------------------------------------------------------------------------
// Scores via MFMA: raw[i][j] = (2*dot128(q_i,k_j) - qs_i - ks_j)/8, j>i -> -1e30.
// 128x128 tile, K=128 single-shot, 8 waves (2x4, 64x32 each). grid (8,8,128).
// ---------------------------------------------------------------------------
__global__ void __launch_bounds__(512) score_k(Args P) {
    const int bh = blockIdx.z;
    const int m0 = blockIdx.y * 128, n0 = blockIdx.x * 128;
    if (n0 > m0) return;
    __shared__ unsigned short Qs[128][128];
    __shared__ unsigned short Ks[128][128];
    const unsigned short *qc = P.qcat + (size_t)bh * SLEN * 128;
    const unsigned short *kc = P.kcat + (size_t)bh * SLEN * 128;
    const int t = threadIdx.x;
#pragma unroll
    for (int it = 0; it < 4; ++it) {
        int g = t + 512 * it;
        int r = g >> 4, cg = g & 15;
        *(bf16x8 *)&Qs[r][((cg ^ (r & 7))) * 8] = *(const bf16x8 *)(qc + (size_t)(m0 + r) * 128 + cg * 8);
        *(bf16x8 *)&Ks[r][((cg ^ (r & 7))) * 8] = *(const bf16x8 *)(kc + (size_t)(n0 + r) * 128 + cg * 8);
    }
    __syncthreads();
    const int wid = t >> 6, lane = t & 63;
    const int wm = wid >> 2, wn = wid & 3;    // 2 x 4 waves, each 64x32
    const int l16 = lane & 15, lq = lane >> 4;

    f32x4 acc[4][2];
#pragma unroll
    for (int i = 0; i < 4; ++i)
#pragma unroll
        for (int j = 0; j < 2; ++j) acc[i][j] = (f32x4)(0.f);

#pragma unroll
    for (int kk = 0; kk < 4; ++kk) {
        bf16x8 a[4], b[2];
#pragma unroll
        for (int mf = 0; mf < 4; ++mf) {
            int r = wm * 64 + mf * 16 + l16;
            int cg = kk * 4 + lq;
            a[mf] = *(const bf16x8 *)&Qs[r][(cg ^ (r & 7)) * 8];
        }
#pragma unroll
        for (int nf = 0; nf < 2; ++nf) {
            int r = wn * 32 + nf * 16 + l16;
            int cg = kk * 4 + lq;
            b[nf] = *(const bf16x8 *)&Ks[r][(cg ^ (r & 7)) * 8];
        }
#pragma unroll
        for (int mf = 0; mf < 4; ++mf)
#pragma unroll
            for (int nf = 0; nf < 2; ++nf)
                acc[mf][nf] = __builtin_amdgcn_mfma_f32_16x16x32_bf16(a[mf], b[nf], acc[mf][nf], 0, 0, 0);
    }

    const float *qsum = P.sums + (size_t)bh * SLEN;
    const float *ksum = P.sums + BHROWS + (size_t)bh * SLEN;
    float *probs = P.probs + (size_t)bh * SLEN * SLEN;
#pragma unroll
    for (int mf = 0; mf < 4; ++mf) {
#pragma unroll
        for (int r = 0; r < 4; ++r) {
            const int i = m0 + wm * 64 + mf * 16 + lq * 4 + r;
            const float qs = qsum[i];
#pragma unroll
            for (int nf = 0; nf < 2; ++nf) {
                const int j = n0 + wn * 32 + nf * 16 + l16;
                float sv = (2.f * acc[mf][nf][r] - qs - ksum[j]) * 0.125f;
                probs[(size_t)i * SLEN + j] = (j > i) ? -1e30f : sv;
            }
        }
    }
}

// ---------------------------------------------------------------------------
// In-place row softmax (fp32). One 256-thread block per row. Exact zeros in
// the masked tail; row i==0 zeroed (zero_pad).
// ---------------------------------------------------------------------------
__global__ void __launch_bounds__(256) softmax_k(float *probs) {
    const long long row = blockIdx.x;
    const int i = (int)(row & (SLEN - 1));
    float *p = probs + row * SLEN;
    const int kend = (i & ~127) + 128;
    const int t = threadIdx.x;
    const bool activ = (t * 4) < kend;

    float4 v = make_float4(-1e30f, -1e30f, -1e30f, -1e30f);
    if (activ) v = ((const float4 *)p)[t];

    float m = fmaxf(fmaxf(v.x, v.y), fmaxf(v.z, v.w));
    __shared__ float smax[4];
    __shared__ float ssum[4];
    const int wv = t >> 6, lane = t & 63;
#pragma unroll
    for (int o = 32; o > 0; o >>= 1) m = fmaxf(m, __shfl_xor(m, o));
    if (lane == 0) smax[wv] = m;
    __syncthreads();
    m = fmaxf(fmaxf(smax[0], smax[1]), fmaxf(smax[2], smax[3]));

    float e0 = 0.f, e1 = 0.f, e2 = 0.f, e3 = 0.f;
    if (activ) {
        e0 = expf(v.x - m); e1 = expf(v.y - m);
        e2 = expf(v.z - m); e3 = expf(v.w - m);
    }
    float s = e0 + e1 + e2 + e3;
#pragma unroll
    for (int o = 32; o > 0; o >>= 1) s += __shfl_xor(s, o);
    if (lane == 0) ssum[wv] = s;
    __syncthreads();
    const float total = ssum[0] + ssum[1] + ssum[2] + ssum[3];

    const float scale = (i == 0) ? 0.f : (1.f / total);
    ((float4 *)p)[t] = make_float4(e0 * scale, e1 * scale, e2 * scale, e3 * scale);
}

// ---------------------------------------------------------------------------
// PV via MFMA: ctx_m = P @ mv, ctx_c = P^2 @ cv. 128(q) x 128(d: mv|cv) tile,
// 4 waves 2x2: wn=0 -> P/mean half, wn=1 -> P^2/cov half. K over j, step 64,
// causal-trimmed; long tiles dispatched first. grid (8, 128) x 256.
// ---------------------------------------------------------------------------
__global__ void __launch_bounds__(256) pv_k(Args P) {
    const int bh = blockIdx.y;
    const int m0 = (7 - blockIdx.x) * 128;
    __shared__ unsigned short Ps[128][64];
    __shared__ unsigned short Ps2[128][64];
    __shared__ unsigned short Vt[128][64];
    const float *pb = P.probs + (size_t)bh * SLEN * SLEN;
    const unsigned short *vt = P.vcat_t + (size_t)bh * 128 * SLEN;
    const int t = threadIdx.x;
    const int wid = t >> 6, lane = t & 63;
    const int wm = wid >> 1, wn = wid & 1;
    const int l16 = lane & 15, lq = lane >> 4;

    f32x4 acc[4][4];
#pragma unroll
    for (int i = 0; i < 4; ++i)
#pragma unroll
        for (int j = 0; j < 4; ++j) acc[i][j] = (f32x4)(0.f);

    const int nst = (m0 >> 6) + 2;
    for (int st = 0; st < nst; ++st) {
        const int j0 = st * 64;
        __syncthreads();
#pragma unroll
        for (int it = 0; it < 4; ++it) {
            int g = t + 256 * it;
            int r = g >> 3, cg = g & 7;
            const float *pp = pb + (size_t)(m0 + r) * SLEN + j0 + cg * 8;
            float4 v0 = *(const float4 *)pp;
            float4 v1 = *(const float4 *)(pp + 4);
            float x[8] = {v0.x, v0.y, v0.z, v0.w, v1.x, v1.y, v1.z, v1.w};
            u16x8 pv, pv2;
#pragma unroll
            for (int e = 0; e < 8; ++e) { pv[e] = f2bf(x[e]); pv2[e] = f2bf(x[e] * x[e]); }
            *(u16x8 *)&Ps[r][(cg ^ (r & 7)) * 8] = pv;
            *(u16x8 *)&Ps2[r][(cg ^ (r & 7)) * 8] = pv2;
            *(u16x8 *)&Vt[r][(cg ^ (r & 7)) * 8] = *(const u16x8 *)(vt + (size_t)r * SLEN + j0 + cg * 8);
        }
        __syncthreads();
#pragma unroll
        for (int kk = 0; kk < 2; ++kk) {
            bf16x8 a[4], b[4];
#pragma unroll
            for (int mf = 0; mf < 4; ++mf) {
                int r = wm * 64 + mf * 16 + l16;
                int cg = kk * 4 + lq;
                a[mf] = wn ? *(const bf16x8 *)&Ps2[r][(cg ^ (r & 7)) * 8]
                           : *(const bf16x8 *)&Ps[r][(cg ^ (r & 7)) * 8];
            }
#pragma unroll
            for (int nf = 0; nf < 4; ++nf) {
                int d = wn * 64 + nf * 16 + l16;
                int cg = kk * 4 + lq;
                b[nf] = *(const bf16x8 *)&Vt[d][(cg ^ (d & 7)) * 8];
            }
#pragma unroll
            for (int mf = 0; mf < 4; ++mf)
#pragma unroll
                for (int nf = 0; nf < 4; ++nf)
                    acc[mf][nf] = __builtin_amdgcn_mfma_f32_16x16x32_bf16(a[mf], b[nf], acc[mf][nf], 0, 0, 0);
        }
    }

    unsigned short *dst = wn ? P.ctxc : P.ctxm;
    const int b_ = bh >> 3, h_ = bh & 7;
#pragma unroll
    for (int mf = 0; mf < 4; ++mf) {
#pragma unroll
        for (int nf = 0; nf < 4; ++nf) {
#pragma unroll
            for (int r = 0; r < 4; ++r) {
                const int s_ = m0 + wm * 64 + mf * 16 + lq * 4 + r;
                const int col = h_ * 64 + nf * 16 + l16;
                dst[((size_t)b_ * SLEN + s_) * HDIM + col] = f2bf(acc[mf][nf][r]);
            }
        }
    }
}

// ---------------------------------------------------------------------------
// LayerNorm: one wave per row of tmp0/tmp1 -> out_m/out_c.
// ---------------------------------------------------------------------------
__global__ void __launch_bounds__(256) ln_k(Args P) {
    const int t = threadIdx.x;
    const int wv = t >> 6, lane = t & 63;
    const long long rid = (long long)blockIdx.x * 4 + wv;    // 0..32767
    const float *src = (rid < NROWS) ? P.tmp0 : P.tmp1;
    float *dst = (rid < NROWS) ? P.out_m : P.out_c;
    const long long r = rid & (NROWS - 1);
    const float *p = src + r * HDIM;

    float4 v1 = ((const float4 *)p)[lane * 2];
    float4 v2 = ((const float4 *)p)[lane * 2 + 1];
    float s = v1.x + v1.y + v1.z + v1.w + v2.x + v2.y + v2.z + v2.w;
    float ss = v1.x * v1.x + v1.y * v1.y + v1.z * v1.z + v1.w * v1.w
             + v2.x * v2.x + v2.y * v2.y + v2.z * v2.z + v2.w * v2.w;
#pragma unroll
    for (int o = 32; o > 0; o >>= 1) { s += __shfl_xor(s, o); ss += __shfl_xor(ss, o); }

    const float mean = s * (1.f / 512.f);
    const float var = ss * (1.f / 512.f) - mean * mean;
    const float inv = 1.f / sqrtf(var + 1e-12f);
    const int c0 = lane * 8;

    float x[8] = {v1.x, v1.y, v1.z, v1.w, v2.x, v2.y, v2.z, v2.w};
    float o[8];
#pragma unroll
    for (int e = 0; e < 8; ++e)
        o[e] = P.ln_w[c0 + e] * ((x[e] - mean) * inv) + P.ln_b[c0 + e];
    float *q = dst + r * HDIM + c0;
    *(float4 *)q = make_float4(o[0], o[1], o[2], o[3]);
    *(float4 *)(q + 4) = make_float4(o[4], o[5], o[6], o[7]);
}

// ---------------------------------------------------------------------------
extern "C" void kernel_launch(void *const *d_in, const int *in_sizes, int n_in,
                              void *d_out, int out_size, void *d_ws, size_t ws_size,
                              hipStream_t stream) {
    (void)in_sizes; (void)n_in; (void)out_size; (void)ws_size;
    Args P;
    P.xm  = (const float *)d_in[0];
    P.xrm = (const float *)d_in[1];
    P.xc  = (const float *)d_in[2];
    P.xrc = (const float *)d_in[3];
    // d_in[4] = attn_mask: exactly where(causal,0,-1e4); -1e4 underflows to an
    // exact 0 probability, reproduced bit-exactly by causal handling.
    for (int i = 0; i < 8; ++i) {
        P.w[i]    = (const float *)d_in[5 + 2 * i];
        P.bias[i] = (const float *)d_in[6 + 2 * i];
    }
    P.ln_w = (const float *)d_in[21];
    P.ln_b = (const float *)d_in[22];

    char *ws = (char *)d_ws;
    P.xbf    = (unsigned short *)(ws);
    P.vcat_t = (unsigned short *)(ws);                 // alias, xbf dead by then
    P.wt     = (unsigned short *)(ws + 67108864);
    P.sums   = (float *)(ws + 71303168);
    P.qcat   = (unsigned short *)(ws + 72351744);
    P.ctxm   = (unsigned short *)(ws + 72351744);      // alias, qcat dead
    P.ctxc   = (unsigned short *)(ws + 89128960);
    P.kcat   = (unsigned short *)(ws + 105906176);
    P.tmp0   = (float *)(ws + 105906176);              // alias, kcat dead
    P.vcat   = (unsigned short *)(ws + 139460608);
    P.tmp1   = (float *)(ws + 139460608);              // alias, vcat dead

    P.out_m = (float *)d_out;
    P.out_c = (float *)d_out + 8388608;
    P.probs = (float *)d_out + 16777216;

    cvt_inputs_k<<<dim3(4096, 4), dim3(256), 0, stream>>>(P);
    wtrans_k<<<dim3(64, 8), dim3(256), 0, stream>>>(P);
    mgemm_k<0><<<dim3(4, 128, 6), dim3(256), 0, stream>>>(P);
    vtrans_k<<<dim3(8, 128), dim3(256), 0, stream>>>(P);
    rowsum_k<<<dim3(65536), dim3(256), 0, stream>>>(P);
    score_k<<<dim3(8, 8, 128), dim3(512), 0, stream>>>(P);
    softmax_k<<<dim3(131072), dim3(256), 0, stream>>>(P.probs);
    pv_k<<<dim3(8, 128), dim3(256), 0, stream>>>(P);
    mgemm_k<1><<<dim3(4, 128, 2), dim3(256), 0, stream>>>(P);
    ln_k<<<dim3(8192), dim3(256), 0, stream>>>(P);
}

// Round 6
// 595.926 us; speedup vs baseline: 3.6376x; 1.2806x over previous
//
#include <hip/hip_runtime.h>
#include <math.h>

// Problem constants
#define SLEN 1024
#define NH 8
#define DH 64
#define HDIM 512
#define BATCH 16
#define NROWS (BATCH * SLEN)          // 16384
#define BHN (BATCH * NH)              // 128
#define BHROWS (BHN * SLEN)           // 131072

typedef short bf16x8 __attribute__((ext_vector_type(8)));
typedef unsigned short u16x8 __attribute__((ext_vector_type(8)));
typedef float f32x4 __attribute__((ext_vector_type(4)));

__device__ __forceinline__ unsigned short f2bf(float f) {
    unsigned u = __float_as_uint(f);
    u += 0x7fffu + ((u >> 16) & 1u);           // RNE
    return (unsigned short)(u >> 16);
}
__device__ __forceinline__ float bf2f(unsigned short h) {
    return __uint_as_float(((unsigned)h) << 16);
}

// ---------------------------------------------------------------------------
// Workspace layout (BYTE offsets). Peak 173,015,040 B.
//   xbf      @ 0          : 4 x 16,777,216 (xm,xrm,xc,xrc bf16)   [dead after proj]
//   vcat_t   @ 0          : 33,554,432 (aliases xbf[0..2))        [written by vtrans]
//   ctxm     @ 33,554,432 : 16,777,216 bf16 (aliases xbf[2..3))   [written by flash]
//   ctxc     @ 50,331,648 : 16,777,216 bf16 (aliases xbf[3..4))
//   wt       @ 67,108,864 : 8 x 524,288 (W^T bf16 [n][k])
//   sums     @ 71,303,168 : 1,048,576 (qsum|ksum fp32)
//   qcat     @ 72,351,744 : 33,554,432 bf16 [bh][s][128]          [live through flash]
//   kcat     @105,906,176 : 33,554,432                            [dead after flash]
//     tmp0   @105,906,176 : 33,554,432 fp32
//   vcat     @139,460,608 : 33,554,432                            [dead after vtrans]
//     tmp1   @139,460,608 : 33,554,432 fp32
// ---------------------------------------------------------------------------
struct Args {
    const float *xm, *xrm, *xc, *xrc;
    const float *w[8], *bias[8];
    const float *ln_w, *ln_b;
    unsigned short *xbf, *wt;
    float *sums;
    unsigned short *qcat, *kcat, *vcat, *vcat_t, *ctxm, *ctxc;
    float *tmp0, *tmp1;
    float *out_m, *out_c, *probs;
};

// ---------------------------------------------------------------------------
// Convert the 4 fp32 activation inputs to bf16. grid (4096, 4) x 256.
// ---------------------------------------------------------------------------
__global__ void __launch_bounds__(256) cvt_inputs_k(Args P) {
    const int which = blockIdx.y;
    const float *s = which == 0 ? P.xm : which == 1 ? P.xrm : which == 2 ? P.xc : P.xrc;
    unsigned short *d = P.xbf + (size_t)which * 8388608;
    const long long i = ((long long)blockIdx.x * 256 + threadIdx.x) * 8;
    if (i >= 8388608) return;          // safety guard
    float4 a = *(const float4 *)(s + i);
    float4 b = *(const float4 *)(s + i + 4);
    u16x8 o;
    o[0] = f2bf(a.x); o[1] = f2bf(a.y); o[2] = f2bf(a.z); o[3] = f2bf(a.w);
    o[4] = f2bf(b.x); o[5] = f2bf(b.y); o[6] = f2bf(b.z); o[7] = f2bf(b.w);
    *(u16x8 *)(d + i) = o;
}

// ---------------------------------------------------------------------------
// Transpose+convert the 8 weight matrices: WT[n][k] = bf16(W[k][n]).
// ---------------------------------------------------------------------------
__global__ void __launch_bounds__(256) wtrans_k(Args P) {
    const int op = blockIdx.y;
    const float *W = P.w[op];
    unsigned short *WT = P.wt + (size_t)op * 262144;
    const int kt = blockIdx.x >> 3, nt = blockIdx.x & 7;
    __shared__ float Ws[64][65];
    const int t = threadIdx.x;
#pragma unroll
    for (int it = 0; it < 4; ++it) {
        int g = t + 256 * it;
        int k = g >> 4, n4 = (g & 15) * 4;
        float4 v = *(const float4 *)(W + (size_t)(kt * 64 + k) * 512 + nt * 64 + n4);
        Ws[k][n4] = v.x; Ws[k][n4 + 1] = v.y; Ws[k][n4 + 2] = v.z; Ws[k][n4 + 3] = v.w;
    }
    __syncthreads();
#pragma unroll
    for (int it = 0; it < 2; ++it) {
        int g = t + 256 * it;
        int n = g >> 3, kg = (g & 7) * 8;
        u16x8 o;
#pragma unroll
        for (int e = 0; e < 8; ++e) o[e] = f2bf(Ws[kg + e][n]);
        *(u16x8 *)(WT + (size_t)(nt * 64 + n) * 512 + kt * 64 + kg) = o;
    }
}

// ---------------------------------------------------------------------------
// bf16 MFMA GEMM, 128x128 tile, BK=64, 4 waves (2x2, 64x64 each).
// MODE 0: C = bf16act(Xbf @ WT^T + bias) -> qcat/kcat/vcat [bh][s][128]
// MODE 1: C = ctx @ WT^T + bias + resid -> tmp fp32 [16384][512]
// ---------------------------------------------------------------------------
template <int MODE>
__global__ void __launch_bounds__(256) mgemm_k(Args P) {
    const int op = blockIdx.z;
    const unsigned short *Abf, *WT;
    const float *bias;
    const float *resid = nullptr;
    unsigned short *dstb = nullptr;
    float *dstf = nullptr;
    int doff = 0, act = 0;
    if (MODE == 0) {
        const int srcidx[6] = {0, 0, 1, 2, 2, 3};
        Abf = P.xbf + (size_t)srcidx[op] * 8388608;
        WT = P.wt + (size_t)op * 262144;
        bias = P.bias[op];
        switch (op) {
            case 0: dstb = P.qcat; doff = 0;  act = 0; break;
            case 1: dstb = P.kcat; doff = 0;  act = 0; break;
            case 2: dstb = P.vcat; doff = 0;  act = 0; break;
            case 3: dstb = P.qcat; doff = 64; act = 1; break;
            case 4: dstb = P.kcat; doff = 64; act = 1; break;
            default:dstb = P.vcat; doff = 64; act = 2; break;
        }
    } else {
        Abf = (op == 0) ? P.ctxm : P.ctxc;
        WT = P.wt + (size_t)(6 + op) * 262144;
        bias = P.bias[6 + op];
        resid = (op == 0) ? P.xm : P.xc;
        dstf = (op == 0) ? P.tmp0 : P.tmp1;
    }
    const int m0 = blockIdx.y * 128, n0 = blockIdx.x * 128;

    __shared__ unsigned short As[128][64];
    __shared__ unsigned short Bs[128][64];
    const int t = threadIdx.x;
    const int wid = t >> 6, lane = t & 63;
    const int wm = wid >> 1, wn = wid & 1;
    const int l16 = lane & 15, lq = lane >> 4;

    f32x4 acc[4][4];
#pragma unroll
    for (int i = 0; i < 4; ++i)
#pragma unroll
        for (int j = 0; j < 4; ++j) acc[i][j] = (f32x4)(0.f);

    for (int k0 = 0; k0 < 512; k0 += 64) {
        __syncthreads();
#pragma unroll
        for (int it = 0; it < 4; ++it) {
            int g = t + 256 * it;
            int r = g >> 3, cg = g & 7;
            bf16x8 av = *(const bf16x8 *)(Abf + (size_t)(m0 + r) * 512 + k0 + cg * 8);
            *(bf16x8 *)&As[r][(cg ^ (r & 7)) * 8] = av;
            bf16x8 bv = *(const bf16x8 *)(WT + (size_t)(n0 + r) * 512 + k0 + cg * 8);
            *(bf16x8 *)&Bs[r][(cg ^ (r & 7)) * 8] = bv;
        }
        __syncthreads();
#pragma unroll
        for (int kk = 0; kk < 2; ++kk) {
            bf16x8 a[4], b[4];
#pragma unroll
            for (int mf = 0; mf < 4; ++mf) {
                int r = wm * 64 + mf * 16 + l16;
                int cg = kk * 4 + lq;
                a[mf] = *(const bf16x8 *)&As[r][(cg ^ (r & 7)) * 8];
            }
#pragma unroll
            for (int nf = 0; nf < 4; ++nf) {
                int r = wn * 64 + nf * 16 + l16;
                int cg = kk * 4 + lq;
                b[nf] = *(const bf16x8 *)&Bs[r][(cg ^ (r & 7)) * 8];
            }
#pragma unroll
            for (int mf = 0; mf < 4; ++mf)
#pragma unroll
                for (int nf = 0; nf < 4; ++nf)
                    acc[mf][nf] = __builtin_amdgcn_mfma_f32_16x16x32_bf16(a[mf], b[nf], acc[mf][nf], 0, 0, 0);
        }
    }

#pragma unroll
    for (int mf = 0; mf < 4; ++mf) {
#pragma unroll
        for (int nf = 0; nf < 4; ++nf) {
#pragma unroll
            for (int r = 0; r < 4; ++r) {
                const int i = m0 + wm * 64 + mf * 16 + lq * 4 + r;
                const int j = n0 + wn * 64 + nf * 16 + l16;
                float v = acc[mf][nf][r] + bias[j];
                if (MODE == 0) {
                    if (act == 1) {
                        float e = v > 0.f ? v + 1.f : expf(v);
                        v = sqrtf(fmaxf(e, 1e-24f));
                    } else if (act == 2) {
                        v = v > 0.f ? v + 1.f : expf(v);
                    }
                    const int b_ = i >> 10, s_ = i & (SLEN - 1);
                    const int h_ = j >> 6, d_ = j & (DH - 1);
                    dstb[((size_t)(b_ * NH + h_) * SLEN + s_) * 128 + doff + d_] = f2bf(v);
                } else {
                    v += resid[(size_t)i * HDIM + j];
                    dstf[(size_t)i * HDIM + j] = v;
                }
            }
        }
    }
}

// ---------------------------------------------------------------------------
// Transpose vcat [bh][s][128] -> vcat_t [bh][d][1024]. grid (8, 128) x 256.
// ---------------------------------------------------------------------------
__global__ void __launch_bounds__(256) vtrans_k(Args P) {
    const int bh = blockIdx.y;
    const int s0 = blockIdx.x * 128;
    __shared__ unsigned short Ts[128][136];
    const unsigned short *src = P.vcat + (size_t)bh * SLEN * 128;
    unsigned short *dst = P.vcat_t + (size_t)bh * 128 * SLEN;
    const int t = threadIdx.x;
#pragma unroll
    for (int it = 0; it < 8; ++it) {
        int g = t + 256 * it;
        int s = g >> 4, dg = g & 15;
        *(u16x8 *)&Ts[s][dg * 8] = *(const u16x8 *)(src + (size_t)(s0 + s) * 128 + dg * 8);
    }
    __syncthreads();
#pragma unroll
    for (int it = 0; it < 8; ++it) {
        int g = t + 256 * it;
        int d = g >> 4, sg = g & 15;
        u16x8 o;
#pragma unroll
        for (int e = 0; e < 8; ++e) o[e] = Ts[sg * 8 + e][d];
        *(u16x8 *)(dst + (size_t)d * SLEN + s0 + sg * 8) = o;
    }
}

// ---------------------------------------------------------------------------
// Row sums from bf16 qcat/kcat (consistent with MFMA operand values).
// ---------------------------------------------------------------------------
__global__ void __launch_bounds__(256) rowsum_k(Args P) {
    const int t = threadIdx.x;
    const int wv = t >> 6, lane = t & 63;
    const long long row = (long long)blockIdx.x * 4 + wv;    // 0..262143
    const unsigned short *src = (row < BHROWS) ? P.qcat : P.kcat;
    const long long r = row & (BHROWS - 1);
    const unsigned short *p = src + r * 128;
    float a = bf2f(p[lane]), b = bf2f(p[64 + lane]);
    float v = a * a + b * b;
#pragma unroll
    for (int o = 32; o > 0; o >>= 1) v += __shfl_xor(v, o);
    if (lane == 0) P.sums[row] = v;
}

// ---------------------------------------------------------------------------
// Fused flash attention: scores -> exp (no max-subtraction; scores <= ~0 by
// construction) -> probs write (normalized, single pass) -> PV (mean + cov).
// Block = 64 q-rows of one (b,h); 512 threads = 8 waves.
//   wave w: mg = w>>1 owns 16 q-rows (mg*16..+15); half = w&1:
//     phase 1: half selects 32 of the 64 k-cols per k-tile
//     phase 2: half 0 -> mean (E, V d 0..63), half 1 -> cov (E^2, V d 64..127)
// LDS: E panel [64][1024] bf16 (128 KB, XOR-swizzled 8-elem groups),
//      K tile [64][128] / V tile [128][64] (16 KB, shared), Tsh[64].
// grid (128 bh, 16) with qt = 15 - blockIdx.y (longest first).
// ---------------------------------------------------------------------------
__global__ void __launch_bounds__(512) flash_k(Args P) {
    const int bh = blockIdx.x;
    const int qt = 15 - (int)blockIdx.y;
    const int q0 = qt * 64;
    __shared__ unsigned short Ep[64][1024];    // 128 KB
    __shared__ unsigned short Ks[64][128];     // 16 KB (phase 2 aliases as V)
    __shared__ float Tsh[64];                  // 1/T per row (0 for s==0)
    unsigned short (*Vt)[64] = reinterpret_cast<unsigned short (*)[64]>(&Ks[0][0]);

    const int t = threadIdx.x;
    const int w = t >> 6, lane = t & 63;
    const int l16 = lane & 15, lq = lane >> 4;
    const int mg = w >> 1, half = w & 1;

    const unsigned short *qc = P.qcat + (size_t)bh * SLEN * 128;
    const unsigned short *kc = P.kcat + (size_t)bh * SLEN * 128;
    const float *qsum = P.sums + (size_t)bh * SLEN;
    const float *ksum = P.sums + BHROWS + (size_t)bh * SLEN;

    // Q fragments in registers: row = q0 + mg*16 + l16, k-chunk kk -> group kk*4+lq.
    const unsigned short *qrow = qc + (size_t)(q0 + mg * 16 + l16) * 128;
    bf16x8 qfr[4];
#pragma unroll
    for (int kk = 0; kk < 4; ++kk) qfr[kk] = *(const bf16x8 *)(qrow + (kk * 4 + lq) * 8);
    float qs[4];
#pragma unroll
    for (int r = 0; r < 4; ++r) qs[r] = qsum[q0 + mg * 16 + lq * 4 + r];

    const int nkt = qt + 1;

    // ---- Phase 1: masked exp(scores) into the panel ----
    for (int kt = 0; kt < nkt; ++kt) {
        const int k0 = kt * 64;
        __syncthreads();
#pragma unroll
        for (int it = 0; it < 2; ++it) {       // stage K tile 64x128
            int idx = t + it * 512;
            int r = idx >> 4, g = idx & 15;
            *(bf16x8 *)&Ks[r][(g ^ (r & 7)) * 8] =
                *(const bf16x8 *)(kc + (size_t)(k0 + r) * 128 + g * 8);
        }
        __syncthreads();

        float ks2[2];
#pragma unroll
        for (int nf = 0; nf < 2; ++nf) ks2[nf] = ksum[k0 + half * 32 + nf * 16 + l16];

        f32x4 acc0 = (f32x4)(0.f), acc1 = (f32x4)(0.f);
#pragma unroll
        for (int kk = 0; kk < 4; ++kk) {
            int r0 = half * 32 + l16;
            bf16x8 b0 = *(const bf16x8 *)&Ks[r0][((kk * 4 + lq) ^ (r0 & 7)) * 8];
            acc0 = __builtin_amdgcn_mfma_f32_16x16x32_bf16(qfr[kk], b0, acc0, 0, 0, 0);
            int r1 = half * 32 + 16 + l16;
            bf16x8 b1 = *(const bf16x8 *)&Ks[r1][((kk * 4 + lq) ^ (r1 & 7)) * 8];
            acc1 = __builtin_amdgcn_mfma_f32_16x16x32_bf16(qfr[kk], b1, acc1, 0, 0, 0);
        }
#pragma unroll
        for (int nf = 0; nf < 2; ++nf) {
            const int j = k0 + half * 32 + nf * 16 + l16;
            const float ksv = ks2[nf];
            const f32x4 a = nf ? acc1 : acc0;
#pragma unroll
            for (int r = 0; r < 4; ++r) {
                const int row = mg * 16 + lq * 4 + r;
                const int i = q0 + row;
                float sv = (2.f * a[r] - qs[r] - ksv) * 0.125f;
                float e = (j <= i) ? __expf(sv) : 0.f;
                const int g = j >> 3;
                Ep[row][((g ^ (row & 7)) << 3) | (j & 7)] = f2bf(e);
            }
        }
    }
    __syncthreads();

    // ---- Row totals T (panel sum over the computed k range) ----
    {
        const int row = t >> 3, seg = t & 7;    // 8 threads/row, 16 groups each
        const int glim = nkt * 8;               // valid groups = nkt*64/8
        float s = 0.f;
#pragma unroll
        for (int gi = 0; gi < 16; ++gi) {
            int g = seg * 16 + gi;
            if (g < glim) {
                u16x8 v = *(const u16x8 *)&Ep[row][((g ^ (row & 7)) << 3)];
#pragma unroll
                for (int e = 0; e < 8; ++e) s += bf2f(v[e]);
            }
        }
        s += __shfl_xor(s, 1); s += __shfl_xor(s, 2); s += __shfl_xor(s, 4);
        if (seg == 0) {
            const int i = q0 + row;
            Tsh[row] = (i == 0) ? 0.f : (1.f / s);   // zero_pad row 0
        }
    }
    __syncthreads();

    // ---- Write normalized probs (single full-row pass, exact zeros above diag) ----
    {
        float *pout = P.probs + ((size_t)bh * SLEN + q0) * SLEN;
#pragma unroll
        for (int it = 0; it < 16; ++it) {
            const int row = it * 4 + (t >> 7);
            const int c0 = (t & 127) * 8;
            const int i = q0 + row;
            const float inv = Tsh[row];
            const int g = c0 >> 3;
            u16x8 v = *(const u16x8 *)&Ep[row][((g ^ (row & 7)) << 3)];
            float o[8];
#pragma unroll
            for (int e = 0; e < 8; ++e)
                o[e] = (c0 + e <= i) ? bf2f(v[e]) * inv : 0.f;
            float4 *dst = (float4 *)(pout + (size_t)row * SLEN + c0);
            dst[0] = make_float4(o[0], o[1], o[2], o[3]);
            dst[1] = make_float4(o[4], o[5], o[6], o[7]);
        }
    }

    // ---- Phase 2: PV. half 0: ctx_m = E@V_m; half 1: ctx_c = E^2@V_c ----
    f32x4 pacc[4];
#pragma unroll
    for (int n = 0; n < 4; ++n) pacc[n] = (f32x4)(0.f);
    const unsigned short *vtg = P.vcat_t + (size_t)bh * 128 * SLEN;
    for (int kt = 0; kt < nkt; ++kt) {
        const int k0 = kt * 64;
        __syncthreads();
#pragma unroll
        for (int it = 0; it < 2; ++it) {        // stage V tile 128(d) x 64(k)
            int idx = t + it * 512;
            int d = idx >> 3, g = idx & 7;
            *(bf16x8 *)&Vt[d][(g ^ (d & 7)) * 8] =
                *(const bf16x8 *)(vtg + (size_t)d * SLEN + k0 + g * 8);
        }
        __syncthreads();
#pragma unroll
        for (int kk = 0; kk < 2; ++kk) {
            const int row = mg * 16 + l16;
            const int gg = (k0 >> 3) + kk * 4 + lq;
            bf16x8 af = *(const bf16x8 *)&Ep[row][((gg ^ (row & 7)) << 3)];
            if (half) {                         // cov operand: elementwise square
                u16x8 u = (u16x8)af, sq;
#pragma unroll
                for (int e = 0; e < 8; ++e) {
                    float f = bf2f(u[e]);
                    sq[e] = f2bf(f * f);
                }
                af = (bf16x8)sq;
            }
#pragma unroll
            for (int nf = 0; nf < 4; ++nf) {
                const int d = half * 64 + nf * 16 + l16;
                bf16x8 bf = *(const bf16x8 *)&Vt[d][((kk * 4 + lq) ^ (d & 7)) * 8];
                pacc[nf] = __builtin_amdgcn_mfma_f32_16x16x32_bf16(af, bf, pacc[nf], 0, 0, 0);
            }
        }
    }

    unsigned short *dst = half ? P.ctxc : P.ctxm;
    const int b_ = bh >> 3, h_ = bh & 7;
#pragma unroll
    for (int nf = 0; nf < 4; ++nf) {
#pragma unroll
        for (int r = 0; r < 4; ++r) {
            const int row = mg * 16 + lq * 4 + r;
            const int s_ = q0 + row;
            const float inv = Tsh[row];
            const float scale = half ? inv * inv : inv;   // /T or /T^2 (0 for row 0)
            dst[((size_t)b_ * SLEN + s_) * HDIM + h_ * 64 + nf * 16 + l16] =
                f2bf(pacc[nf][r] * scale);
        }
    }
}

// ---------------------------------------------------------------------------
// LayerNorm: one wave per row of tmp0/tmp1 -> out_m/out_c.
// ---------------------------------------------------------------------------
__global__ void __launch_bounds__(256) ln_k(Args P) {
    const int t = threadIdx.x;
    const int wv = t >> 6, lane = t & 63;
    const long long rid = (long long)blockIdx.x * 4 + wv;    // 0..32767
    const float *src = (rid < NROWS) ? P.tmp0 : P.tmp1;
    float *dst = (rid < NROWS) ? P.out_m : P.out_c;
    const long long r = rid & (NROWS - 1);
    const float *p = src + r * HDIM;

    float4 v1 = ((const float4 *)p)[lane * 2];
    float4 v2 = ((const float4 *)p)[lane * 2 + 1];
    float s = v1.x + v1.y + v1.z + v1.w + v2.x + v2.y + v2.z + v2.w;
    float ss = v1.x * v1.x + v1.y * v1.y + v1.z * v1.z + v1.w * v1.w
             + v2.x * v2.x + v2.y * v2.y + v2.z * v2.z + v2.w * v2.w;
#pragma unroll
    for (int o = 32; o > 0; o >>= 1) { s += __shfl_xor(s, o); ss += __shfl_xor(ss, o); }

    const float mean = s * (1.f / 512.f);
    const float var = ss * (1.f / 512.f) - mean * mean;
    const float inv = 1.f / sqrtf(var + 1e-12f);
    const int c0 = lane * 8;

    float x[8] = {v1.x, v1.y, v1.z, v1.w, v2.x, v2.y, v2.z, v2.w};
    float o[8];
#pragma unroll
    for (int e = 0; e < 8; ++e)
        o[e] = P.ln_w[c0 + e] * ((x[e] - mean) * inv) + P.ln_b[c0 + e];
    float *q = dst + r * HDIM + c0;
    *(float4 *)q = make_float4(o[0], o[1], o[2], o[3]);
    *(float4 *)(q + 4) = make_float4(o[4], o[5], o[6], o[7]);
}

// ---------------------------------------------------------------------------
extern "C" void kernel_launch(void *const *d_in, const int *in_sizes, int n_in,
                              void *d_out, int out_size, void *d_ws, size_t ws_size,
                              hipStream_t stream) {
    (void)in_sizes; (void)n_in; (void)out_size; (void)ws_size;
    Args P;
    P.xm  = (const float *)d_in[0];
    P.xrm = (const float *)d_in[1];
    P.xc  = (const float *)d_in[2];
    P.xrc = (const float *)d_in[3];
    // d_in[4] = attn_mask: exactly where(causal,0,-1e4); the -1e4 branch
    // underflows to an exact 0 probability, reproduced by causal handling.
    for (int i = 0; i < 8; ++i) {
        P.w[i]    = (const float *)d_in[5 + 2 * i];
        P.bias[i] = (const float *)d_in[6 + 2 * i];
    }
    P.ln_w = (const float *)d_in[21];
    P.ln_b = (const float *)d_in[22];

    char *ws = (char *)d_ws;
    P.xbf    = (unsigned short *)(ws);
    P.vcat_t = (unsigned short *)(ws);                 // alias xbf[0..2) (dead)
    P.ctxm   = (unsigned short *)(ws + 33554432);      // alias xbf[2..3) (dead)
    P.ctxc   = (unsigned short *)(ws + 50331648);      // alias xbf[3..4) (dead)
    P.wt     = (unsigned short *)(ws + 67108864);
    P.sums   = (float *)(ws + 71303168);
    P.qcat   = (unsigned short *)(ws + 72351744);      // live through flash_k
    P.kcat   = (unsigned short *)(ws + 105906176);
    P.tmp0   = (float *)(ws + 105906176);              // alias, kcat dead
    P.vcat   = (unsigned short *)(ws + 139460608);
    P.tmp1   = (float *)(ws + 139460608);              // alias, vcat dead

    P.out_m = (float *)d_out;
    P.out_c = (float *)d_out + 8388608;
    P.probs = (float *)d_out + 16777216;

    cvt_inputs_k<<<dim3(4096, 4), dim3(256), 0, stream>>>(P);
    wtrans_k<<<dim3(64, 8), dim3(256), 0, stream>>>(P);
    mgemm_k<0><<<dim3(4, 128, 6), dim3(256), 0, stream>>>(P);
    vtrans_k<<<dim3(8, 128), dim3(256), 0, stream>>>(P);
    rowsum_k<<<dim3(65536), dim3(256), 0, stream>>>(P);
    flash_k<<<dim3(128, 16), dim3(512), 0, stream>>>(P);
    mgemm_k<1><<<dim3(4, 128, 2), dim3(256), 0, stream>>>(P);
    ln_k<<<dim3(8192), dim3(256), 0, stream>>>(P);
}

// Round 8
// 581.369 us; speedup vs baseline: 3.7287x; 1.0250x over previous
//
#include <hip/hip_runtime.h>
#include <math.h>

// Problem constants
#define SLEN 1024
#define NH 8
#define DH 64
#define HDIM 512
#define BATCH 16
#define NROWS (BATCH * SLEN)          // 16384
#define BHN (BATCH * NH)              // 128
#define BHROWS (BHN * SLEN)           // 131072

typedef short bf16x8 __attribute__((ext_vector_type(8)));
typedef unsigned short u16x8 __attribute__((ext_vector_type(8)));
typedef float f32x4 __attribute__((ext_vector_type(4)));

__device__ __forceinline__ unsigned short f2bf(float f) {
    unsigned u = __float_as_uint(f);
    u += 0x7fffu + ((u >> 16) & 1u);           // RNE
    return (unsigned short)(u >> 16);
}
__device__ __forceinline__ float bf2f(unsigned short h) {
    return __uint_as_float(((unsigned)h) << 16);
}

// ---------------------------------------------------------------------------
// Workspace layout (BYTE offsets).
//   xbf      @ 0          : 4 x 16,777,216 (xm,xrm,xc,xrc bf16)   [dead after proj]
//   vcat_t   @ 0          : 33,554,432 (aliases xbf[0..2))        [written by vtrans]
//   ctxm     @ 33,554,432 : 16,777,216 bf16 (aliases xbf[2..3))   [written by flash]
//   ctxc     @ 50,331,648 : 16,777,216 bf16 (aliases xbf[3..4))
//   wt       @ 67,108,864 : 8 x 524,288 (W^T bf16 [n][k])
//   sums     @ 71,303,168 : 1,048,576 (qsum|ksum fp32)
//   qcat     @ 72,351,744 : 33,554,432 bf16 [bh][s][128]          [live through flash]
//   kcat     @105,906,176 : 33,554,432                            [dead after flash]
//   vcat     @139,460,608 : 33,554,432                            [dead after vtrans]
// ---------------------------------------------------------------------------
struct Args {
    const float *xm, *xrm, *xc, *xrc;
    const float *w[8], *bias[8];
    const float *ln_w, *ln_b;
    unsigned short *xbf, *wt;
    float *sums;
    unsigned short *qcat, *kcat, *vcat, *vcat_t, *ctxm, *ctxc;
    float *out_m, *out_c, *probs;
};

// ---------------------------------------------------------------------------
// Convert the 4 fp32 activation inputs to bf16. grid (4096, 4) x 256.
// ---------------------------------------------------------------------------
__global__ void __launch_bounds__(256) cvt_inputs_k(Args P) {
    const int which = blockIdx.y;
    const float *s = which == 0 ? P.xm : which == 1 ? P.xrm : which == 2 ? P.xc : P.xrc;
    unsigned short *d = P.xbf + (size_t)which * 8388608;
    const long long i = ((long long)blockIdx.x * 256 + threadIdx.x) * 8;
    if (i >= 8388608) return;          // safety guard
    float4 a = *(const float4 *)(s + i);
    float4 b = *(const float4 *)(s + i + 4);
    u16x8 o;
    o[0] = f2bf(a.x); o[1] = f2bf(a.y); o[2] = f2bf(a.z); o[3] = f2bf(a.w);
    o[4] = f2bf(b.x); o[5] = f2bf(b.y); o[6] = f2bf(b.z); o[7] = f2bf(b.w);
    *(u16x8 *)(d + i) = o;
}

// ---------------------------------------------------------------------------
// Transpose+convert the 8 weight matrices: WT[n][k] = bf16(W[k][n]).
// ---------------------------------------------------------------------------
__global__ void __launch_bounds__(256) wtrans_k(Args P) {
    const int op = blockIdx.y;
    const float *W = P.w[op];
    unsigned short *WT = P.wt + (size_t)op * 262144;
    const int kt = blockIdx.x >> 3, nt = blockIdx.x & 7;
    __shared__ float Ws[64][65];
    const int t = threadIdx.x;
#pragma unroll
    for (int it = 0; it < 4; ++it) {
        int g = t + 256 * it;
        int k = g >> 4, n4 = (g & 15) * 4;
        float4 v = *(const float4 *)(W + (size_t)(kt * 64 + k) * 512 + nt * 64 + n4);
        Ws[k][n4] = v.x; Ws[k][n4 + 1] = v.y; Ws[k][n4 + 2] = v.z; Ws[k][n4 + 3] = v.w;
    }
    __syncthreads();
#pragma unroll
    for (int it = 0; it < 2; ++it) {
        int g = t + 256 * it;
        int n = g >> 3, kg = (g & 7) * 8;
        u16x8 o;
#pragma unroll
        for (int e = 0; e < 8; ++e) o[e] = f2bf(Ws[kg + e][n]);
        *(u16x8 *)(WT + (size_t)(nt * 64 + n) * 512 + kt * 64 + kg) = o;
    }
}

// ---------------------------------------------------------------------------
// Projection GEMMs (bf16 MFMA), 128x128 tile, BK=64, 4 waves (2x2, 64x64).
// C = bf16act(Xbf @ WT^T + bias) -> qcat/kcat/vcat [bh][s][128].
// XCD-aware swizzle: each XCD owns a contiguous 16-m-tile chunk (2 MB A slice
// + 0.5 MB WT fit its private 4 MB L2), so the 4 n-tiles sharing an A panel
// are L2 hits instead of 4x HBM re-reads.
// ---------------------------------------------------------------------------
__global__ void __launch_bounds__(256) mgemm0_k(Args P) {
    const int op = blockIdx.z;
    const int srcidx[6] = {0, 0, 1, 2, 2, 3};
    const unsigned short *Abf = P.xbf + (size_t)srcidx[op] * 8388608;
    const unsigned short *WT = P.wt + (size_t)op * 262144;
    const float *bias = P.bias[op];
    unsigned short *dstb; int doff, act;
    switch (op) {
        case 0: dstb = P.qcat; doff = 0;  act = 0; break;
        case 1: dstb = P.kcat; doff = 0;  act = 0; break;
        case 2: dstb = P.vcat; doff = 0;  act = 0; break;
        case 3: dstb = P.qcat; doff = 64; act = 1; break;
        case 4: dstb = P.kcat; doff = 64; act = 1; break;
        default:dstb = P.vcat; doff = 64; act = 2; break;
    }
    // XCD swizzle (dispatch idx % 8 == XCD; 512 blocks per op, 512%8==0)
    const int lin = blockIdx.y * 4 + blockIdx.x;       // 0..511
    const int xcd = lin & 7, idx = lin >> 3;           // idx 0..63
    const int m0 = (xcd * 16 + (idx >> 2)) * 128;
    const int n0 = (idx & 3) * 128;

    __shared__ unsigned short As[128][64];
    __shared__ unsigned short Bs[128][64];
    const int t = threadIdx.x;
    const int wid = t >> 6, lane = t & 63;
    const int wm = wid >> 1, wn = wid & 1;
    const int l16 = lane & 15, lq = lane >> 4;

    f32x4 acc[4][4];
#pragma unroll
    for (int i = 0; i < 4; ++i)
#pragma unroll
        for (int j = 0; j < 4; ++j) acc[i][j] = (f32x4)(0.f);

    for (int k0 = 0; k0 < 512; k0 += 64) {
        __syncthreads();
#pragma unroll
        for (int it = 0; it < 4; ++it) {
            int g = t + 256 * it;
            int r = g >> 3, cg = g & 7;
            bf16x8 av = *(const bf16x8 *)(Abf + (size_t)(m0 + r) * 512 + k0 + cg * 8);
            *(bf16x8 *)&As[r][(cg ^ (r & 7)) * 8] = av;
            bf16x8 bv = *(const bf16x8 *)(WT + (size_t)(n0 + r) * 512 + k0 + cg * 8);
            *(bf16x8 *)&Bs[r][(cg ^ (r & 7)) * 8] = bv;
        }
        __syncthreads();
#pragma unroll
        for (int kk = 0; kk < 2; ++kk) {
            bf16x8 a[4], b[4];
#pragma unroll
            for (int mf = 0; mf < 4; ++mf) {
                int r = wm * 64 + mf * 16 + l16;
                int cg = kk * 4 + lq;
                a[mf] = *(const bf16x8 *)&As[r][(cg ^ (r & 7)) * 8];
            }
#pragma unroll
            for (int nf = 0; nf < 4; ++nf) {
                int r = wn * 64 + nf * 16 + l16;
                int cg = kk * 4 + lq;
                b[nf] = *(const bf16x8 *)&Bs[r][(cg ^ (r & 7)) * 8];
            }
#pragma unroll
            for (int mf = 0; mf < 4; ++mf)
#pragma unroll
                for (int nf = 0; nf < 4; ++nf)
                    acc[mf][nf] = __builtin_amdgcn_mfma_f32_16x16x32_bf16(a[mf], b[nf], acc[mf][nf], 0, 0, 0);
        }
    }

#pragma unroll
    for (int mf = 0; mf < 4; ++mf) {
#pragma unroll
        for (int nf = 0; nf < 4; ++nf) {
#pragma unroll
            for (int r = 0; r < 4; ++r) {
                const int i = m0 + wm * 64 + mf * 16 + lq * 4 + r;
                const int j = n0 + wn * 64 + nf * 16 + l16;
                float v = acc[mf][nf][r] + bias[j];
                if (act == 1) {
                    float e = v > 0.f ? v + 1.f : expf(v);
                    v = sqrtf(fmaxf(e, 1e-24f));
                } else if (act == 2) {
                    v = v > 0.f ? v + 1.f : expf(v);
                }
                const int b_ = i >> 10, s_ = i & (SLEN - 1);
                const int h_ = j >> 6, d_ = j & (DH - 1);
                dstb[((size_t)(b_ * NH + h_) * SLEN + s_) * 128 + doff + d_] = f2bf(v);
            }
        }
    }
}

// ---------------------------------------------------------------------------
// Transpose vcat [bh][s][128] -> vcat_t [bh][d][1024]. grid (8, 128) x 256.
// ---------------------------------------------------------------------------
__global__ void __launch_bounds__(256) vtrans_k(Args P) {
    const int bh = blockIdx.y;
    const int s0 = blockIdx.x * 128;
    __shared__ unsigned short Ts[128][136];
    const unsigned short *src = P.vcat + (size_t)bh * SLEN * 128;
    unsigned short *dst = P.vcat_t + (size_t)bh * 128 * SLEN;
    const int t = threadIdx.x;
#pragma unroll
    for (int it = 0; it < 8; ++it) {
        int g = t + 256 * it;
        int s = g >> 4, dg = g & 15;
        *(u16x8 *)&Ts[s][dg * 8] = *(const u16x8 *)(src + (size_t)(s0 + s) * 128 + dg * 8);
    }
    __syncthreads();
#pragma unroll
    for (int it = 0; it < 8; ++it) {
        int g = t + 256 * it;
        int d = g >> 4, sg = g & 15;
        u16x8 o;
#pragma unroll
        for (int e = 0; e < 8; ++e) o[e] = Ts[sg * 8 + e][d];
        *(u16x8 *)(dst + (size_t)d * SLEN + s0 + sg * 8) = o;
    }
}

// ---------------------------------------------------------------------------
// Row sums from bf16 qcat/kcat (consistent with MFMA operand values).
// ---------------------------------------------------------------------------
__global__ void __launch_bounds__(256) rowsum_k(Args P) {
    const int t = threadIdx.x;
    const int wv = t >> 6, lane = t & 63;
    const long long row = (long long)blockIdx.x * 4 + wv;    // 0..262143
    const unsigned short *src = (row < BHROWS) ? P.qcat : P.kcat;
    const long long r = row & (BHROWS - 1);
    const unsigned short *p = src + r * 128;
    float a = bf2f(p[lane]), b = bf2f(p[64 + lane]);
    float v = a * a + b * b;
#pragma unroll
    for (int o = 32; o > 0; o >>= 1) v += __shfl_xor(v, o);
    if (lane == 0) P.sums[row] = v;
}

// ---------------------------------------------------------------------------
// Fused flash attention: scores -> exp (no max-subtraction; scores <= ~0 by
// construction) -> probs write (normalized, single pass, NT stores) -> PV.
// Block = 64 q-rows of one (b,h); 512 threads = 8 waves.
// Row totals T accumulate in registers during phase 1 (shfl_xor over the
// 16-lane group + tiny LDS cross-wave combine) -- no panel sweep.
// ---------------------------------------------------------------------------
__global__ void __launch_bounds__(512) flash_k(Args P) {
    const int bh = blockIdx.x;
    const int qt = 15 - (int)blockIdx.y;
    const int q0 = qt * 64;
    __shared__ unsigned short Ep[64][1024];    // 128 KB
    __shared__ unsigned short Ks[64][128];     // 16 KB (phase 2 aliases as V)
    __shared__ float Tred[2][64];              // per-half row partials
    __shared__ float Tsh[64];                  // 1/T per row (0 for s==0)
    unsigned short (*Vt)[64] = reinterpret_cast<unsigned short (*)[64]>(&Ks[0][0]);

    const int t = threadIdx.x;
    const int w = t >> 6, lane = t & 63;
    const int l16 = lane & 15, lq = lane >> 4;
    const int mg = w >> 1, half = w & 1;

    const unsigned short *qc = P.qcat + (size_t)bh * SLEN * 128;
    const unsigned short *kc = P.kcat + (size_t)bh * SLEN * 128;
    const float *qsum = P.sums + (size_t)bh * SLEN;
    const float *ksum = P.sums + BHROWS + (size_t)bh * SLEN;

    // Q fragments in registers: row = q0 + mg*16 + l16, k-chunk kk -> group kk*4+lq.
    const unsigned short *qrow = qc + (size_t)(q0 + mg * 16 + l16) * 128;
    bf16x8 qfr[4];
#pragma unroll
    for (int kk = 0; kk < 4; ++kk) qfr[kk] = *(const bf16x8 *)(qrow + (kk * 4 + lq) * 8);
    float qs[4];
#pragma unroll
    for (int r = 0; r < 4; ++r) qs[r] = qsum[q0 + mg * 16 + lq * 4 + r];

    const int nkt = qt + 1;
    float tpart[4] = {0.f, 0.f, 0.f, 0.f};    // fp32 row-total partials

    // ---- Phase 1: masked exp(scores) into the panel ----
    for (int kt = 0; kt < nkt; ++kt) {
        const int k0 = kt * 64;
        __syncthreads();
#pragma unroll
        for (int it = 0; it < 2; ++it) {       // stage K tile 64x128
            int idx = t + it * 512;
            int r = idx >> 4, g = idx & 15;
            *(bf16x8 *)&Ks[r][(g ^ (r & 7)) * 8] =
                *(const bf16x8 *)(kc + (size_t)(k0 + r) * 128 + g * 8);
        }
        __syncthreads();

        float ks2[2];
#pragma unroll
        for (int nf = 0; nf < 2; ++nf) ks2[nf] = ksum[k0 + half * 32 + nf * 16 + l16];

        f32x4 acc0 = (f32x4)(0.f), acc1 = (f32x4)(0.f);
#pragma unroll
        for (int kk = 0; kk < 4; ++kk) {
            int r0 = half * 32 + l16;
            bf16x8 b0 = *(const bf16x8 *)&Ks[r0][((kk * 4 + lq) ^ (r0 & 7)) * 8];
            acc0 = __builtin_amdgcn_mfma_f32_16x16x32_bf16(qfr[kk], b0, acc0, 0, 0, 0);
            int r1 = half * 32 + 16 + l16;
            bf16x8 b1 = *(const bf16x8 *)&Ks[r1][((kk * 4 + lq) ^ (r1 & 7)) * 8];
            acc1 = __builtin_amdgcn_mfma_f32_16x16x32_bf16(qfr[kk], b1, acc1, 0, 0, 0);
        }
#pragma unroll
        for (int nf = 0; nf < 2; ++nf) {
            const int j = k0 + half * 32 + nf * 16 + l16;
            const float ksv = ks2[nf];
            const f32x4 a = nf ? acc1 : acc0;
#pragma unroll
            for (int r = 0; r < 4; ++r) {
                const int row = mg * 16 + lq * 4 + r;
                const int i = q0 + row;
                float sv = (2.f * a[r] - qs[r] - ksv) * 0.125f;
                float e = (j <= i) ? __expf(sv) : 0.f;
                tpart[r] += e;
                const int g = j >> 3;
                Ep[row][((g ^ (row & 7)) << 3) | (j & 7)] = f2bf(e);
            }
        }
    }

    // ---- Row totals: reduce tpart over the 16-lane group, combine halves ----
#pragma unroll
    for (int o = 1; o < 16; o <<= 1)
#pragma unroll
        for (int r = 0; r < 4; ++r) tpart[r] += __shfl_xor(tpart[r], o);
    if (l16 == 0) {
#pragma unroll
        for (int r = 0; r < 4; ++r) Tred[half][mg * 16 + lq * 4 + r] = tpart[r];
    }
    __syncthreads();
    if (t < 64) {
        const int i = q0 + t;
        const float T = Tred[0][t] + Tred[1][t];
        Tsh[t] = (i == 0) ? 0.f : (1.f / T);   // zero_pad row 0
    }
    __syncthreads();

    // ---- Write normalized probs (NT stores; exact zeros above diag) ----
    {
        float *pout = P.probs + ((size_t)bh * SLEN + q0) * SLEN;
#pragma unroll
        for (int it = 0; it < 16; ++it) {
            const int row = it * 4 + (t >> 7);
            const int c0 = (t & 127) * 8;
            const int i = q0 + row;
            const float inv = Tsh[row];
            const int g = c0 >> 3;
            u16x8 v = *(const u16x8 *)&Ep[row][((g ^ (row & 7)) << 3)];
            f32x4 o0, o1;
#pragma unroll
            for (int e = 0; e < 4; ++e)
                o0[e] = (c0 + e <= i) ? bf2f(v[e]) * inv : 0.f;
#pragma unroll
            for (int e = 0; e < 4; ++e)
                o1[e] = (c0 + 4 + e <= i) ? bf2f(v[4 + e]) * inv : 0.f;
            f32x4 *dst = (f32x4 *)(pout + (size_t)row * SLEN + c0);
            __builtin_nontemporal_store(o0, dst);
            __builtin_nontemporal_store(o1, dst + 1);
        }
    }

    // ---- Phase 2: PV. half 0: ctx_m = E@V_m; half 1: ctx_c = E^2@V_c ----
    f32x4 pacc[4];
#pragma unroll
    for (int n = 0; n < 4; ++n) pacc[n] = (f32x4)(0.f);
    const unsigned short *vtg = P.vcat_t + (size_t)bh * 128 * SLEN;
    for (int kt = 0; kt < nkt; ++kt) {
        const int k0 = kt * 64;
        __syncthreads();
#pragma unroll
        for (int it = 0; it < 2; ++it) {        // stage V tile 128(d) x 64(k)
            int idx = t + it * 512;
            int d = idx >> 3, g = idx & 7;
            *(bf16x8 *)&Vt[d][(g ^ (d & 7)) * 8] =
                *(const bf16x8 *)(vtg + (size_t)d * SLEN + k0 + g * 8);
        }
        __syncthreads();
#pragma unroll
        for (int kk = 0; kk < 2; ++kk) {
            const int row = mg * 16 + l16;
            const int gg = (k0 >> 3) + kk * 4 + lq;
            bf16x8 af = *(const bf16x8 *)&Ep[row][((gg ^ (row & 7)) << 3)];
            if (half) {                         // cov operand: elementwise square
                u16x8 u = (u16x8)af, sq;
#pragma unroll
                for (int e = 0; e < 8; ++e) {
                    float f = bf2f(u[e]);
                    sq[e] = f2bf(f * f);
                }
                af = (bf16x8)sq;
            }
#pragma unroll
            for (int nf = 0; nf < 4; ++nf) {
                const int d = half * 64 + nf * 16 + l16;
                bf16x8 bf = *(const bf16x8 *)&Vt[d][((kk * 4 + lq) ^ (d & 7)) * 8];
                pacc[nf] = __builtin_amdgcn_mfma_f32_16x16x32_bf16(af, bf, pacc[nf], 0, 0, 0);
            }
        }
    }

    unsigned short *dst = half ? P.ctxc : P.ctxm;
    const int b_ = bh >> 3, h_ = bh & 7;
#pragma unroll
    for (int nf = 0; nf < 4; ++nf) {
#pragma unroll
        for (int r = 0; r < 4; ++r) {
            const int row = mg * 16 + lq * 4 + r;
            const int s_ = q0 + row;
            const float inv = Tsh[row];
            const float scale = half ? inv * inv : inv;   // /T or /T^2 (0 for row 0)
            dst[((size_t)b_ * SLEN + s_) * HDIM + h_ * 64 + nf * 16 + l16] =
                f2bf(pacc[nf][r] * scale);
        }
    }
}

// ---------------------------------------------------------------------------
// Fused output GEMM + bias + residual + LayerNorm.
// out = LN(ctx @ WT^T + bias + resid).  Tile 64(M) x 512(N, full row), BK=64.
// 512 threads = 8 waves (2 m-bands x 4 n-bands); each wave 32x128 output.
// LN: per-lane partials -> shfl_xor over 16-lane group -> 4-wave LDS combine.
// grid (256 m-tiles, 2 ops).
// ---------------------------------------------------------------------------
__global__ void __launch_bounds__(512, 4) mgemm_ln_k(Args P) {
    const int op = blockIdx.y;
    const unsigned short *Abf = op ? P.ctxc : P.ctxm;
    const unsigned short *WT = P.wt + (size_t)(6 + op) * 262144;
    const float *bias = P.bias[6 + op];
    const float *resid = op ? P.xc : P.xm;
    float *out = op ? P.out_c : P.out_m;
    const int m0 = blockIdx.x * 64;

    __shared__ unsigned short As[64][64];      // 8 KB
    __shared__ unsigned short Bs[512][64];     // 64 KB
    __shared__ float Red[64][4][2];            // 2 KB

    const int t = threadIdx.x;
    const int w = t >> 6, lane = t & 63;
    const int wm = w >> 2, wn = w & 3;         // 2 x 4 waves
    const int l16 = lane & 15, lq = lane >> 4;

    f32x4 acc[2][8];
#pragma unroll
    for (int mf = 0; mf < 2; ++mf)
#pragma unroll
        for (int nf = 0; nf < 8; ++nf) acc[mf][nf] = (f32x4)(0.f);

    for (int k0 = 0; k0 < 512; k0 += 64) {
        __syncthreads();
        {   // stage A: 64 rows x 8 groups = 512 slots, 1/thread
            int r = t >> 3, cg = t & 7;
            *(bf16x8 *)&As[r][(cg ^ (r & 7)) * 8] =
                *(const bf16x8 *)(Abf + (size_t)(m0 + r) * 512 + k0 + cg * 8);
        }
#pragma unroll
        for (int it = 0; it < 8; ++it) {       // stage B: 512 rows x 8 groups
            int g = t + 512 * it;
            int r = g >> 3, cg = g & 7;
            *(bf16x8 *)&Bs[r][(cg ^ (r & 7)) * 8] =
                *(const bf16x8 *)(WT + (size_t)r * 512 + k0 + cg * 8);
        }
        __syncthreads();
#pragma unroll
        for (int kk = 0; kk < 2; ++kk) {
            bf16x8 a[2];
#pragma unroll
            for (int mf = 0; mf < 2; ++mf) {
                int r = wm * 32 + mf * 16 + l16;
                a[mf] = *(const bf16x8 *)&As[r][((kk * 4 + lq) ^ (r & 7)) * 8];
            }
#pragma unroll
            for (int nf = 0; nf < 8; ++nf) {
                int rn = wn * 128 + nf * 16 + l16;
                bf16x8 b = *(const bf16x8 *)&Bs[rn][((kk * 4 + lq) ^ (rn & 7)) * 8];
#pragma unroll
                for (int mf = 0; mf < 2; ++mf)
                    acc[mf][nf] = __builtin_amdgcn_mfma_f32_16x16x32_bf16(a[mf], b, acc[mf][nf], 0, 0, 0);
            }
        }
    }

    // epilogue: bias + resid accumulated in place; LN partials per (mf,r)
    float bv[8];
#pragma unroll
    for (int nf = 0; nf < 8; ++nf) bv[nf] = bias[wn * 128 + nf * 16 + l16];

    float s0[2][4], s1[2][4];
#pragma unroll
    for (int mf = 0; mf < 2; ++mf)
#pragma unroll
        for (int r = 0; r < 4; ++r) { s0[mf][r] = 0.f; s1[mf][r] = 0.f; }

#pragma unroll
    for (int mf = 0; mf < 2; ++mf) {
#pragma unroll
        for (int r = 0; r < 4; ++r) {
            const int i = m0 + wm * 32 + mf * 16 + lq * 4 + r;
            const float *rrow = resid + (size_t)i * HDIM + wn * 128 + l16;
#pragma unroll
            for (int nf = 0; nf < 8; ++nf) {
                float x = acc[mf][nf][r] + bv[nf] + rrow[nf * 16];
                acc[mf][nf][r] = x;
                s0[mf][r] += x;
                s1[mf][r] += x * x;
            }
        }
    }
#pragma unroll
    for (int o = 1; o < 16; o <<= 1)
#pragma unroll
        for (int mf = 0; mf < 2; ++mf)
#pragma unroll
            for (int r = 0; r < 4; ++r) {
                s0[mf][r] += __shfl_xor(s0[mf][r], o);
                s1[mf][r] += __shfl_xor(s1[mf][r], o);
            }
    if (l16 == 0) {
#pragma unroll
        for (int mf = 0; mf < 2; ++mf)
#pragma unroll
            for (int r = 0; r < 4; ++r) {
                const int row = wm * 32 + mf * 16 + lq * 4 + r;
                Red[row][wn][0] = s0[mf][r];
                Red[row][wn][1] = s1[mf][r];
            }
    }
    __syncthreads();

    float lnw[8], lnb[8];
#pragma unroll
    for (int nf = 0; nf < 8; ++nf) {
        const int j = wn * 128 + nf * 16 + l16;
        lnw[nf] = P.ln_w[j]; lnb[nf] = P.ln_b[j];
    }
#pragma unroll
    for (int mf = 0; mf < 2; ++mf) {
#pragma unroll
        for (int r = 0; r < 4; ++r) {
            const int row = wm * 32 + mf * 16 + lq * 4 + r;
            const int i = m0 + row;
            const float S  = Red[row][0][0] + Red[row][1][0] + Red[row][2][0] + Red[row][3][0];
            const float SS = Red[row][0][1] + Red[row][1][1] + Red[row][2][1] + Red[row][3][1];
            const float mean = S * (1.f / 512.f);
            const float var = SS * (1.f / 512.f) - mean * mean;
            const float inv = 1.f / sqrtf(var + 1e-12f);
            float *orow = out + (size_t)i * HDIM + wn * 128 + l16;
#pragma unroll
            for (int nf = 0; nf < 8; ++nf)
                orow[nf * 16] = lnw[nf] * ((acc[mf][nf][r] - mean) * inv) + lnb[nf];
        }
    }
}

// ---------------------------------------------------------------------------
extern "C" void kernel_launch(void *const *d_in, const int *in_sizes, int n_in,
                              void *d_out, int out_size, void *d_ws, size_t ws_size,
                              hipStream_t stream) {
    (void)in_sizes; (void)n_in; (void)out_size; (void)ws_size;
    Args P;
    P.xm  = (const float *)d_in[0];
    P.xrm = (const float *)d_in[1];
    P.xc  = (const float *)d_in[2];
    P.xrc = (const float *)d_in[3];
    // d_in[4] = attn_mask: exactly where(causal,0,-1e4); the -1e4 branch
    // underflows to an exact 0 probability, reproduced by causal handling.
    for (int i = 0; i < 8; ++i) {
        P.w[i]    = (const float *)d_in[5 + 2 * i];
        P.bias[i] = (const float *)d_in[6 + 2 * i];
    }
    P.ln_w = (const float *)d_in[21];
    P.ln_b = (const float *)d_in[22];

    char *ws = (char *)d_ws;
    P.xbf    = (unsigned short *)(ws);
    P.vcat_t = (unsigned short *)(ws);                 // alias xbf[0..2) (dead)
    P.ctxm   = (unsigned short *)(ws + 33554432);      // alias xbf[2..3) (dead)
    P.ctxc   = (unsigned short *)(ws + 50331648);      // alias xbf[3..4) (dead)
    P.wt     = (unsigned short *)(ws + 67108864);
    P.sums   = (float *)(ws + 71303168);
    P.qcat   = (unsigned short *)(ws + 72351744);      // live through flash_k
    P.kcat   = (unsigned short *)(ws + 105906176);
    P.vcat   = (unsigned short *)(ws + 139460608);

    P.out_m = (float *)d_out;
    P.out_c = (float *)d_out + 8388608;
    P.probs = (float *)d_out + 16777216;

    cvt_inputs_k<<<dim3(4096, 4), dim3(256), 0, stream>>>(P);
    wtrans_k<<<dim3(64, 8), dim3(256), 0, stream>>>(P);
    mgemm0_k<<<dim3(4, 128, 6), dim3(256), 0, stream>>>(P);
    vtrans_k<<<dim3(8, 128), dim3(256), 0, stream>>>(P);
    rowsum_k<<<dim3(65536), dim3(256), 0, stream>>>(P);
    flash_k<<<dim3(128, 16), dim3(512), 0, stream>>>(P);
    mgemm_ln_k<<<dim3(256, 2), dim3(512), 0, stream>>>(P);
}

// Round 9
// 540.308 us; speedup vs baseline: 4.0120x; 1.0760x over previous
//
#include <hip/hip_runtime.h>
#include <math.h>

// Problem constants
#define SLEN 1024
#define NH 8
#define DH 64
#define HDIM 512
#define BATCH 16
#define NROWS (BATCH * SLEN)          // 16384
#define BHN (BATCH * NH)              // 128
#define BHROWS (BHN * SLEN)           // 131072

typedef short bf16x8 __attribute__((ext_vector_type(8)));
typedef unsigned short u16x8 __attribute__((ext_vector_type(8)));
typedef float f32x4 __attribute__((ext_vector_type(4)));

__device__ __forceinline__ unsigned short f2bf(float f) {
    unsigned u = __float_as_uint(f);
    u += 0x7fffu + ((u >> 16) & 1u);           // RNE
    return (unsigned short)(u >> 16);
}
__device__ __forceinline__ float bf2f(unsigned short h) {
    return __uint_as_float(((unsigned)h) << 16);
}

// ---------------------------------------------------------------------------
// Workspace layout (BYTE offsets).
//   xbf      @ 0          : 4 x 16,777,216 (xm,xrm,xc,xrc bf16)   [dead after proj]
//   vcat_t   @ 0          : 33,554,432 (aliases xbf[0..2))        [written by vtrans]
//   ctxm     @ 33,554,432 : 16,777,216 bf16 (aliases xbf[2..3))   [written by flash]
//   ctxc     @ 50,331,648 : 16,777,216 bf16 (aliases xbf[3..4))
//   wt       @ 67,108,864 : 8 x 524,288 (W^T bf16 [n][k])
//   sums     @ 71,303,168 : 1,048,576 (qsum|ksum fp32)
//   qcat     @ 72,351,744 : 33,554,432 bf16 [bh][s][128]          [live through flash]
//   kcat     @105,906,176 : 33,554,432                            [dead after flash]
//   vcat     @139,460,608 : 33,554,432                            [dead after vtrans]
// ---------------------------------------------------------------------------
struct Args {
    const float *xm, *xrm, *xc, *xrc;
    const float *w[8], *bias[8];
    const float *ln_w, *ln_b;
    unsigned short *xbf, *wt;
    float *sums;
    unsigned short *qcat, *kcat, *vcat, *vcat_t, *ctxm, *ctxc;
    float *out_m, *out_c, *probs;
};

// ---------------------------------------------------------------------------
// Convert the 4 fp32 activation inputs to bf16. grid (4096, 4) x 256.
// ---------------------------------------------------------------------------
__global__ void __launch_bounds__(256) cvt_inputs_k(Args P) {
    const int which = blockIdx.y;
    const float *s = which == 0 ? P.xm : which == 1 ? P.xrm : which == 2 ? P.xc : P.xrc;
    unsigned short *d = P.xbf + (size_t)which * 8388608;
    const long long i = ((long long)blockIdx.x * 256 + threadIdx.x) * 8;
    if (i >= 8388608) return;          // safety guard
    float4 a = *(const float4 *)(s + i);
    float4 b = *(const float4 *)(s + i + 4);
    u16x8 o;
    o[0] = f2bf(a.x); o[1] = f2bf(a.y); o[2] = f2bf(a.z); o[3] = f2bf(a.w);
    o[4] = f2bf(b.x); o[5] = f2bf(b.y); o[6] = f2bf(b.z); o[7] = f2bf(b.w);
    *(u16x8 *)(d + i) = o;
}

// ---------------------------------------------------------------------------
// Transpose+convert the 8 weight matrices: WT[n][k] = bf16(W[k][n]).
// ---------------------------------------------------------------------------
__global__ void __launch_bounds__(256) wtrans_k(Args P) {
    const int op = blockIdx.y;
    const float *W = P.w[op];
    unsigned short *WT = P.wt + (size_t)op * 262144;
    const int kt = blockIdx.x >> 3, nt = blockIdx.x & 7;
    __shared__ float Ws[64][65];
    const int t = threadIdx.x;
#pragma unroll
    for (int it = 0; it < 4; ++it) {
        int g = t + 256 * it;
        int k = g >> 4, n4 = (g & 15) * 4;
        float4 v = *(const float4 *)(W + (size_t)(kt * 64 + k) * 512 + nt * 64 + n4);
        Ws[k][n4] = v.x; Ws[k][n4 + 1] = v.y; Ws[k][n4 + 2] = v.z; Ws[k][n4 + 3] = v.w;
    }
    __syncthreads();
#pragma unroll
    for (int it = 0; it < 2; ++it) {
        int g = t + 256 * it;
        int n = g >> 3, kg = (g & 7) * 8;
        u16x8 o;
#pragma unroll
        for (int e = 0; e < 8; ++e) o[e] = f2bf(Ws[kg + e][n]);
        *(u16x8 *)(WT + (size_t)(nt * 64 + n) * 512 + kt * 64 + kg) = o;
    }
}

// ---------------------------------------------------------------------------
// Projection GEMMs (bf16 MFMA), 128x128 tile, BK=64, 4 waves (2x2, 64x64).
// C = bf16act(Xbf @ WT^T + bias) -> qcat/kcat/vcat [bh][s][128].
// XCD-aware swizzle: each XCD owns a contiguous 16-m-tile chunk (2 MB A slice
// + 0.5 MB WT fit its private 4 MB L2).
// ---------------------------------------------------------------------------
__global__ void __launch_bounds__(256) mgemm0_k(Args P) {
    const int op = blockIdx.z;
    const int srcidx[6] = {0, 0, 1, 2, 2, 3};
    const unsigned short *Abf = P.xbf + (size_t)srcidx[op] * 8388608;
    const unsigned short *WT = P.wt + (size_t)op * 262144;
    const float *bias = P.bias[op];
    unsigned short *dstb; int doff, act;
    switch (op) {
        case 0: dstb = P.qcat; doff = 0;  act = 0; break;
        case 1: dstb = P.kcat; doff = 0;  act = 0; break;
        case 2: dstb = P.vcat; doff = 0;  act = 0; break;
        case 3: dstb = P.qcat; doff = 64; act = 1; break;
        case 4: dstb = P.kcat; doff = 64; act = 1; break;
        default:dstb = P.vcat; doff = 64; act = 2; break;
    }
    // XCD swizzle (dispatch idx % 8 == XCD; 512 blocks per op, 512%8==0)
    const int lin = blockIdx.y * 4 + blockIdx.x;       // 0..511
    const int xcd = lin & 7, idx = lin >> 3;           // idx 0..63
    const int m0 = (xcd * 16 + (idx >> 2)) * 128;
    const int n0 = (idx & 3) * 128;

    __shared__ unsigned short As[128][64];
    __shared__ unsigned short Bs[128][64];
    const int t = threadIdx.x;
    const int wid = t >> 6, lane = t & 63;
    const int wm = wid >> 1, wn = wid & 1;
    const int l16 = lane & 15, lq = lane >> 4;

    f32x4 acc[4][4];
#pragma unroll
    for (int i = 0; i < 4; ++i)
#pragma unroll
        for (int j = 0; j < 4; ++j) acc[i][j] = (f32x4)(0.f);

    for (int k0 = 0; k0 < 512; k0 += 64) {
        __syncthreads();
#pragma unroll
        for (int it = 0; it < 4; ++it) {
            int g = t + 256 * it;
            int r = g >> 3, cg = g & 7;
            bf16x8 av = *(const bf16x8 *)(Abf + (size_t)(m0 + r) * 512 + k0 + cg * 8);
            *(bf16x8 *)&As[r][(cg ^ (r & 7)) * 8] = av;
            bf16x8 bv = *(const bf16x8 *)(WT + (size_t)(n0 + r) * 512 + k0 + cg * 8);
            *(bf16x8 *)&Bs[r][(cg ^ (r & 7)) * 8] = bv;
        }
        __syncthreads();
#pragma unroll
        for (int kk = 0; kk < 2; ++kk) {
            bf16x8 a[4], b[4];
#pragma unroll
            for (int mf = 0; mf < 4; ++mf) {
                int r = wm * 64 + mf * 16 + l16;
                int cg = kk * 4 + lq;
                a[mf] = *(const bf16x8 *)&As[r][(cg ^ (r & 7)) * 8];
            }
#pragma unroll
            for (int nf = 0; nf < 4; ++nf) {
                int r = wn * 64 + nf * 16 + l16;
                int cg = kk * 4 + lq;
                b[nf] = *(const bf16x8 *)&Bs[r][(cg ^ (r & 7)) * 8];
            }
#pragma unroll
            for (int mf = 0; mf < 4; ++mf)
#pragma unroll
                for (int nf = 0; nf < 4; ++nf)
                    acc[mf][nf] = __builtin_amdgcn_mfma_f32_16x16x32_bf16(a[mf], b[nf], acc[mf][nf], 0, 0, 0);
        }
    }

#pragma unroll
    for (int mf = 0; mf < 4; ++mf) {
#pragma unroll
        for (int nf = 0; nf < 4; ++nf) {
#pragma unroll
            for (int r = 0; r < 4; ++r) {
                const int i = m0 + wm * 64 + mf * 16 + lq * 4 + r;
                const int j = n0 + wn * 64 + nf * 16 + l16;
                float v = acc[mf][nf][r] + bias[j];
                if (act == 1) {
                    float e = v > 0.f ? v + 1.f : expf(v);
                    v = sqrtf(fmaxf(e, 1e-24f));
                } else if (act == 2) {
                    v = v > 0.f ? v + 1.f : expf(v);
                }
                const int b_ = i >> 10, s_ = i & (SLEN - 1);
                const int h_ = j >> 6, d_ = j & (DH - 1);
                dstb[((size_t)(b_ * NH + h_) * SLEN + s_) * 128 + doff + d_] = f2bf(v);
            }
        }
    }
}

// ---------------------------------------------------------------------------
// Transpose vcat [bh][s][128] -> vcat_t [bh][d][1024]. grid (8, 128) x 256.
// ---------------------------------------------------------------------------
__global__ void __launch_bounds__(256) vtrans_k(Args P) {
    const int bh = blockIdx.y;
    const int s0 = blockIdx.x * 128;
    __shared__ unsigned short Ts[128][136];
    const unsigned short *src = P.vcat + (size_t)bh * SLEN * 128;
    unsigned short *dst = P.vcat_t + (size_t)bh * 128 * SLEN;
    const int t = threadIdx.x;
#pragma unroll
    for (int it = 0; it < 8; ++it) {
        int g = t + 256 * it;
        int s = g >> 4, dg = g & 15;
        *(u16x8 *)&Ts[s][dg * 8] = *(const u16x8 *)(src + (size_t)(s0 + s) * 128 + dg * 8);
    }
    __syncthreads();
#pragma unroll
    for (int it = 0; it < 8; ++it) {
        int g = t + 256 * it;
        int d = g >> 4, sg = g & 15;
        u16x8 o;
#pragma unroll
        for (int e = 0; e < 8; ++e) o[e] = Ts[sg * 8 + e][d];
        *(u16x8 *)(dst + (size_t)d * SLEN + s0 + sg * 8) = o;
    }
}

// ---------------------------------------------------------------------------
// Row sums from bf16 qcat/kcat (consistent with MFMA operand values).
// ---------------------------------------------------------------------------
__global__ void __launch_bounds__(256) rowsum_k(Args P) {
    const int t = threadIdx.x;
    const int wv = t >> 6, lane = t & 63;
    const long long row = (long long)blockIdx.x * 4 + wv;    // 0..262143
    const unsigned short *src = (row < BHROWS) ? P.qcat : P.kcat;
    const long long r = row & (BHROWS - 1);
    const unsigned short *p = src + r * 128;
    float a = bf2f(p[lane]), b = bf2f(p[64 + lane]);
    float v = a * a + b * b;
#pragma unroll
    for (int o = 32; o > 0; o >>= 1) v += __shfl_xor(v, o);
    if (lane == 0) P.sums[row] = v;
}

// ---------------------------------------------------------------------------
// Fused flash attention, 1024 threads = 16 waves (4 waves/SIMD for latency
// hiding; round-8 fix for the 22%-occupancy latency-bound profile).
// Block = 64 q-rows of one (b,h). Wave w: mg = w>>2 owns rows mg*16..+15;
// q4 = w&3 owns k-cols q4*16..+15 per tile (phase 1) / d-strip q4*32 (phase 2).
// LDS: E panel [64][1024] bf16 (128 KB, XOR-swizzled), K/V tile 16 KB
// (aliased), Tred/Tsh ~1.3 KB -> ~145.5 KB, 1 block/CU.
// Plain (non-NT) probs stores: NT showed ~1.5x HBM write amplification.
// ---------------------------------------------------------------------------
__global__ void __launch_bounds__(1024, 4) flash_k(Args P) {
    const int bh = blockIdx.x;
    const int qt = 15 - (int)blockIdx.y;
    const int q0 = qt * 64;
    __shared__ unsigned short Ep[64][1024];    // 128 KB
    __shared__ unsigned short Ks[64][128];     // 16 KB (phase 2 aliases as V)
    __shared__ float Tred[4][64];              // per-quarter row partials
    __shared__ float Tsh[64];                  // 1/T per row (0 for s==0)
    unsigned short (*Vt)[64] = reinterpret_cast<unsigned short (*)[64]>(&Ks[0][0]);

    const int t = threadIdx.x;
    const int w = t >> 6, lane = t & 63;
    const int l16 = lane & 15, lq = lane >> 4;
    const int mg = w >> 2, q4 = w & 3;

    const unsigned short *qc = P.qcat + (size_t)bh * SLEN * 128;
    const unsigned short *kc = P.kcat + (size_t)bh * SLEN * 128;
    const float *qsum = P.sums + (size_t)bh * SLEN;
    const float *ksum = P.sums + BHROWS + (size_t)bh * SLEN;

    // Q fragments: row = q0 + mg*16 + l16, k-group kk*4+lq (covers 128 dims).
    const unsigned short *qrow = qc + (size_t)(q0 + mg * 16 + l16) * 128;
    bf16x8 qfr[4];
#pragma unroll
    for (int kk = 0; kk < 4; ++kk) qfr[kk] = *(const bf16x8 *)(qrow + (kk * 4 + lq) * 8);
    float qs[4];
#pragma unroll
    for (int r = 0; r < 4; ++r) qs[r] = qsum[q0 + mg * 16 + lq * 4 + r];

    const int nkt = qt + 1;
    float tpart[4] = {0.f, 0.f, 0.f, 0.f};    // fp32 row-total partials

    // ---- Phase 1: masked exp(scores) into the panel ----
    for (int kt = 0; kt < nkt; ++kt) {
        const int k0 = kt * 64;
        __syncthreads();
        {   // stage K tile 64x128 = 16 KB in one shot (1024 x 16 B)
            int r = t >> 4, g = t & 15;
            *(bf16x8 *)&Ks[r][(g ^ (r & 7)) * 8] =
                *(const bf16x8 *)(kc + (size_t)(k0 + r) * 128 + g * 8);
        }
        __syncthreads();

        const int rK = q4 * 16 + l16;
        const float ksv = ksum[k0 + rK];
        f32x4 acc = (f32x4)(0.f);
#pragma unroll
        for (int kk = 0; kk < 4; ++kk) {
            bf16x8 b = *(const bf16x8 *)&Ks[rK][((kk * 4 + lq) ^ (rK & 7)) * 8];
            acc = __builtin_amdgcn_mfma_f32_16x16x32_bf16(qfr[kk], b, acc, 0, 0, 0);
        }
        const int j = k0 + rK;
#pragma unroll
        for (int r = 0; r < 4; ++r) {
            const int row = mg * 16 + lq * 4 + r;
            const int i = q0 + row;
            float sv = (2.f * acc[r] - qs[r] - ksv) * 0.125f;
            float e = (j <= i) ? __expf(sv) : 0.f;
            tpart[r] += e;
            Ep[row][(((j >> 3) ^ (row & 7)) << 3) | (j & 7)] = f2bf(e);
        }
    }

    // ---- Row totals: reduce over the 16-lane group, combine 4 quarters ----
#pragma unroll
    for (int o = 1; o < 16; o <<= 1)
#pragma unroll
        for (int r = 0; r < 4; ++r) tpart[r] += __shfl_xor(tpart[r], o);
    if (l16 == 0) {
#pragma unroll
        for (int r = 0; r < 4; ++r) Tred[q4][mg * 16 + lq * 4 + r] = tpart[r];
    }
    __syncthreads();
    if (t < 64) {
        const int i = q0 + t;
        const float T = Tred[0][t] + Tred[1][t] + Tred[2][t] + Tred[3][t];
        Tsh[t] = (i == 0) ? 0.f : (1.f / T);   // zero_pad row 0
    }
    __syncthreads();

    // ---- Write normalized probs (plain stores; exact zeros above diag) ----
    {
        float *pout = P.probs + ((size_t)bh * SLEN + q0) * SLEN;
#pragma unroll
        for (int it = 0; it < 8; ++it) {
            const int row = it * 8 + (t >> 7);
            const int c0 = (t & 127) * 8;
            const int i = q0 + row;
            const float inv = Tsh[row];
            const int g = c0 >> 3;
            u16x8 v = *(const u16x8 *)&Ep[row][((g ^ (row & 7)) << 3)];
            f32x4 o0, o1;
#pragma unroll
            for (int e = 0; e < 4; ++e)
                o0[e] = (c0 + e <= i) ? bf2f(v[e]) * inv : 0.f;
#pragma unroll
            for (int e = 0; e < 4; ++e)
                o1[e] = (c0 + 4 + e <= i) ? bf2f(v[4 + e]) * inv : 0.f;
            f32x4 *dst = (f32x4 *)(pout + (size_t)row * SLEN + c0);
            dst[0] = o0;
            dst[1] = o1;
        }
    }

    // ---- Phase 2: PV. q4<2: ctx_m strip (E@V_m); q4>=2: ctx_c (E^2@V_c) ----
    const int cov = q4 >> 1;
    f32x4 pacc[2];
    pacc[0] = (f32x4)(0.f); pacc[1] = (f32x4)(0.f);
    const unsigned short *vtg = P.vcat_t + (size_t)bh * 128 * SLEN;
    for (int kt = 0; kt < nkt; ++kt) {
        const int k0 = kt * 64;
        __syncthreads();
        {   // stage V tile 128(d) x 64(k) = 16 KB in one shot
            int d = t >> 3, g = t & 7;
            *(bf16x8 *)&Vt[d][(g ^ (d & 7)) * 8] =
                *(const bf16x8 *)(vtg + (size_t)d * SLEN + k0 + g * 8);
        }
        __syncthreads();
#pragma unroll
        for (int kk = 0; kk < 2; ++kk) {
            const int row = mg * 16 + l16;
            const int gg = (k0 >> 3) + kk * 4 + lq;
            bf16x8 af = *(const bf16x8 *)&Ep[row][((gg ^ (row & 7)) << 3)];
            if (cov) {                          // cov operand: elementwise square
                u16x8 u = (u16x8)af, sq;
#pragma unroll
                for (int e = 0; e < 8; ++e) {
                    float f = bf2f(u[e]);
                    sq[e] = f2bf(f * f);
                }
                af = (bf16x8)sq;
            }
#pragma unroll
            for (int nf = 0; nf < 2; ++nf) {
                const int d = q4 * 32 + nf * 16 + l16;
                bf16x8 bf = *(const bf16x8 *)&Vt[d][((kk * 4 + lq) ^ (d & 7)) * 8];
                pacc[nf] = __builtin_amdgcn_mfma_f32_16x16x32_bf16(af, bf, pacc[nf], 0, 0, 0);
            }
        }
    }

    unsigned short *dst = cov ? P.ctxc : P.ctxm;
    const int b_ = bh >> 3, h_ = bh & 7;
#pragma unroll
    for (int nf = 0; nf < 2; ++nf) {
#pragma unroll
        for (int r = 0; r < 4; ++r) {
            const int row = mg * 16 + lq * 4 + r;
            const int s_ = q0 + row;
            const float inv = Tsh[row];
            const float scale = cov ? inv * inv : inv;    // /T or /T^2 (0 for row 0)
            dst[((size_t)b_ * SLEN + s_) * HDIM + h_ * 64 + (q4 & 1) * 32 + nf * 16 + l16] =
                f2bf(pacc[nf][r] * scale);
        }
    }
}

// ---------------------------------------------------------------------------
// Fused output GEMM + bias + residual + LayerNorm.
// out = LN(ctx @ WT^T + bias + resid).  Tile 64(M) x 512(N, full row), BK=64.
// 512 threads = 8 waves (2 m-bands x 4 n-bands); each wave 32x128 output.
// grid (256 m-tiles, 2 ops).
// ---------------------------------------------------------------------------
__global__ void __launch_bounds__(512, 4) mgemm_ln_k(Args P) {
    const int op = blockIdx.y;
    const unsigned short *Abf = op ? P.ctxc : P.ctxm;
    const unsigned short *WT = P.wt + (size_t)(6 + op) * 262144;
    const float *bias = P.bias[6 + op];
    const float *resid = op ? P.xc : P.xm;
    float *out = op ? P.out_c : P.out_m;
    const int m0 = blockIdx.x * 64;

    __shared__ unsigned short As[64][64];      // 8 KB
    __shared__ unsigned short Bs[512][64];     // 64 KB
    __shared__ float Red[64][4][2];            // 2 KB

    const int t = threadIdx.x;
    const int w = t >> 6, lane = t & 63;
    const int wm = w >> 2, wn = w & 3;         // 2 x 4 waves
    const int l16 = lane & 15, lq = lane >> 4;

    f32x4 acc[2][8];
#pragma unroll
    for (int mf = 0; mf < 2; ++mf)
#pragma unroll
        for (int nf = 0; nf < 8; ++nf) acc[mf][nf] = (f32x4)(0.f);

    for (int k0 = 0; k0 < 512; k0 += 64) {
        __syncthreads();
        {   // stage A: 64 rows x 8 groups = 512 slots, 1/thread
            int r = t >> 3, cg = t & 7;
            *(bf16x8 *)&As[r][(cg ^ (r & 7)) * 8] =
                *(const bf16x8 *)(Abf + (size_t)(m0 + r) * 512 + k0 + cg * 8);
        }
#pragma unroll
        for (int it = 0; it < 8; ++it) {       // stage B: 512 rows x 8 groups
            int g = t + 512 * it;
            int r = g >> 3, cg = g & 7;
            *(bf16x8 *)&Bs[r][(cg ^ (r & 7)) * 8] =
                *(const bf16x8 *)(WT + (size_t)r * 512 + k0 + cg * 8);
        }
        __syncthreads();
#pragma unroll
        for (int kk = 0; kk < 2; ++kk) {
            bf16x8 a[2];
#pragma unroll
            for (int mf = 0; mf < 2; ++mf) {
                int r = wm * 32 + mf * 16 + l16;
                a[mf] = *(const bf16x8 *)&As[r][((kk * 4 + lq) ^ (r & 7)) * 8];
            }
#pragma unroll
            for (int nf = 0; nf < 8; ++nf) {
                int rn = wn * 128 + nf * 16 + l16;
                bf16x8 b = *(const bf16x8 *)&Bs[rn][((kk * 4 + lq) ^ (rn & 7)) * 8];
#pragma unroll
                for (int mf = 0; mf < 2; ++mf)
                    acc[mf][nf] = __builtin_amdgcn_mfma_f32_16x16x32_bf16(a[mf], b, acc[mf][nf], 0, 0, 0);
            }
        }
    }

    // epilogue: bias + resid accumulated in place; LN partials per (mf,r)
    float bv[8];
#pragma unroll
    for (int nf = 0; nf < 8; ++nf) bv[nf] = bias[wn * 128 + nf * 16 + l16];

    float s0[2][4], s1[2][4];
#pragma unroll
    for (int mf = 0; mf < 2; ++mf)
#pragma unroll
        for (int r = 0; r < 4; ++r) { s0[mf][r] = 0.f; s1[mf][r] = 0.f; }

#pragma unroll
    for (int mf = 0; mf < 2; ++mf) {
#pragma unroll
        for (int r = 0; r < 4; ++r) {
            const int i = m0 + wm * 32 + mf * 16 + lq * 4 + r;
            const float *rrow = resid + (size_t)i * HDIM + wn * 128 + l16;
#pragma unroll
            for (int nf = 0; nf < 8; ++nf) {
                float x = acc[mf][nf][r] + bv[nf] + rrow[nf * 16];
                acc[mf][nf][r] = x;
                s0[mf][r] += x;
                s1[mf][r] += x * x;
            }
        }
    }
#pragma unroll
    for (int o = 1; o < 16; o <<= 1)
#pragma unroll
        for (int mf = 0; mf < 2; ++mf)
#pragma unroll
            for (int r = 0; r < 4; ++r) {
                s0[mf][r] += __shfl_xor(s0[mf][r], o);
                s1[mf][r] += __shfl_xor(s1[mf][r], o);
            }
    if (l16 == 0) {
#pragma unroll
        for (int mf = 0; mf < 2; ++mf)
#pragma unroll
            for (int r = 0; r < 4; ++r) {
                const int row = wm * 32 + mf * 16 + lq * 4 + r;
                Red[row][wn][0] = s0[mf][r];
                Red[row][wn][1] = s1[mf][r];
            }
    }
    __syncthreads();

    float lnw[8], lnb[8];
#pragma unroll
    for (int nf = 0; nf < 8; ++nf) {
        const int j = wn * 128 + nf * 16 + l16;
        lnw[nf] = P.ln_w[j]; lnb[nf] = P.ln_b[j];
    }
#pragma unroll
    for (int mf = 0; mf < 2; ++mf) {
#pragma unroll
        for (int r = 0; r < 4; ++r) {
            const int row = wm * 32 + mf * 16 + lq * 4 + r;
            const int i = m0 + row;
            const float S  = Red[row][0][0] + Red[row][1][0] + Red[row][2][0] + Red[row][3][0];
            const float SS = Red[row][0][1] + Red[row][1][1] + Red[row][2][1] + Red[row][3][1];
            const float mean = S * (1.f / 512.f);
            const float var = SS * (1.f / 512.f) - mean * mean;
            const float inv = 1.f / sqrtf(var + 1e-12f);
            float *orow = out + (size_t)i * HDIM + wn * 128 + l16;
#pragma unroll
            for (int nf = 0; nf < 8; ++nf)
                orow[nf * 16] = lnw[nf] * ((acc[mf][nf][r] - mean) * inv) + lnb[nf];
        }
    }
}

// ---------------------------------------------------------------------------
extern "C" void kernel_launch(void *const *d_in, const int *in_sizes, int n_in,
                              void *d_out, int out_size, void *d_ws, size_t ws_size,
                              hipStream_t stream) {
    (void)in_sizes; (void)n_in; (void)out_size; (void)ws_size;
    Args P;
    P.xm  = (const float *)d_in[0];
    P.xrm = (const float *)d_in[1];
    P.xc  = (const float *)d_in[2];
    P.xrc = (const float *)d_in[3];
    // d_in[4] = attn_mask: exactly where(causal,0,-1e4); the -1e4 branch
    // underflows to an exact 0 probability, reproduced by causal handling.
    for (int i = 0; i < 8; ++i) {
        P.w[i]    = (const float *)d_in[5 + 2 * i];
        P.bias[i] = (const float *)d_in[6 + 2 * i];
    }
    P.ln_w = (const float *)d_in[21];
    P.ln_b = (const float *)d_in[22];

    char *ws = (char *)d_ws;
    P.xbf    = (unsigned short *)(ws);
    P.vcat_t = (unsigned short *)(ws);                 // alias xbf[0..2) (dead)
    P.ctxm   = (unsigned short *)(ws + 33554432);      // alias xbf[2..3) (dead)
    P.ctxc   = (unsigned short *)(ws + 50331648);      // alias xbf[3..4) (dead)
    P.wt     = (unsigned short *)(ws + 67108864);
    P.sums   = (float *)(ws + 71303168);
    P.qcat   = (unsigned short *)(ws + 72351744);      // live through flash_k
    P.kcat   = (unsigned short *)(ws + 105906176);
    P.vcat   = (unsigned short *)(ws + 139460608);

    P.out_m = (float *)d_out;
    P.out_c = (float *)d_out + 8388608;
    P.probs = (float *)d_out + 16777216;

    cvt_inputs_k<<<dim3(4096, 4), dim3(256), 0, stream>>>(P);
    wtrans_k<<<dim3(64, 8), dim3(256), 0, stream>>>(P);
    mgemm0_k<<<dim3(4, 128, 6), dim3(256), 0, stream>>>(P);
    vtrans_k<<<dim3(8, 128), dim3(256), 0, stream>>>(P);
    rowsum_k<<<dim3(65536), dim3(256), 0, stream>>>(P);
    flash_k<<<dim3(128, 16), dim3(1024), 0, stream>>>(P);
    mgemm_ln_k<<<dim3(256, 2), dim3(512), 0, stream>>>(P);
}

// Round 10
// 485.231 us; speedup vs baseline: 4.4674x; 1.1135x over previous
//
#include <hip/hip_runtime.h>
#include <math.h>

// Problem constants
#define SLEN 1024
#define NH 8
#define DH 64
#define HDIM 512
#define BATCH 16
#define NROWS (BATCH * SLEN)          // 16384
#define BHN (BATCH * NH)              // 128
#define BHROWS (BHN * SLEN)           // 131072

typedef short bf16x8 __attribute__((ext_vector_type(8)));
typedef unsigned short u16x8 __attribute__((ext_vector_type(8)));
typedef float f32x4 __attribute__((ext_vector_type(4)));

__device__ __forceinline__ unsigned short f2bf(float f) {
    unsigned u = __float_as_uint(f);
    u += 0x7fffu + ((u >> 16) & 1u);           // RNE
    return (unsigned short)(u >> 16);
}
__device__ __forceinline__ float bf2f(unsigned short h) {
    return __uint_as_float(((unsigned)h) << 16);
}

// ---------------------------------------------------------------------------
// Workspace layout (BYTE offsets).
//   xbf      @ 0          : 4 x 16,777,216 (xm,xrm,xc,xrc bf16)   [dead after proj]
//   vcat_t   @ 0          : 33,554,432 (aliases xbf[0..2))        [written by vtrans]
//   ctxm     @ 33,554,432 : 16,777,216 bf16 (aliases xbf[2..3))   [written by flash]
//   ctxc     @ 50,331,648 : 16,777,216 bf16 (aliases xbf[3..4))
//   wt       @ 67,108,864 : 8 x 524,288 (W^T bf16 [n][k])
//   sums     @ 71,303,168 : 1,048,576 (qsum|ksum fp32)
//   qcat     @ 72,351,744 : 33,554,432 bf16 [bh][s][128]          [live through flash]
//   kcat     @105,906,176 : 33,554,432                            [dead after flash]
//   vcat     @139,460,608 : 33,554,432                            [dead after vtrans]
// ---------------------------------------------------------------------------
struct Args {
    const float *xm, *xrm, *xc, *xrc;
    const float *w[8], *bias[8];
    const float *ln_w, *ln_b;
    unsigned short *xbf, *wt;
    float *sums;
    unsigned short *qcat, *kcat, *vcat, *vcat_t, *ctxm, *ctxc;
    float *out_m, *out_c, *probs;
};

// ---------------------------------------------------------------------------
// Convert the 4 fp32 activation inputs to bf16. grid (4096, 4) x 256.
// ---------------------------------------------------------------------------
__global__ void __launch_bounds__(256) cvt_inputs_k(Args P) {
    const int which = blockIdx.y;
    const float *s = which == 0 ? P.xm : which == 1 ? P.xrm : which == 2 ? P.xc : P.xrc;
    unsigned short *d = P.xbf + (size_t)which * 8388608;
    const long long i = ((long long)blockIdx.x * 256 + threadIdx.x) * 8;
    if (i >= 8388608) return;          // safety guard
    float4 a = *(const float4 *)(s + i);
    float4 b = *(const float4 *)(s + i + 4);
    u16x8 o;
    o[0] = f2bf(a.x); o[1] = f2bf(a.y); o[2] = f2bf(a.z); o[3] = f2bf(a.w);
    o[4] = f2bf(b.x); o[5] = f2bf(b.y); o[6] = f2bf(b.z); o[7] = f2bf(b.w);
    *(u16x8 *)(d + i) = o;
}

// ---------------------------------------------------------------------------
// Transpose+convert the 8 weight matrices: WT[n][k] = bf16(W[k][n]).
// ---------------------------------------------------------------------------
__global__ void __launch_bounds__(256) wtrans_k(Args P) {
    const int op = blockIdx.y;
    const float *W = P.w[op];
    unsigned short *WT = P.wt + (size_t)op * 262144;
    const int kt = blockIdx.x >> 3, nt = blockIdx.x & 7;
    __shared__ float Ws[64][65];
    const int t = threadIdx.x;
#pragma unroll
    for (int it = 0; it < 4; ++it) {
        int g = t + 256 * it;
        int k = g >> 4, n4 = (g & 15) * 4;
        float4 v = *(const float4 *)(W + (size_t)(kt * 64 + k) * 512 + nt * 64 + n4);
        Ws[k][n4] = v.x; Ws[k][n4 + 1] = v.y; Ws[k][n4 + 2] = v.z; Ws[k][n4 + 3] = v.w;
    }
    __syncthreads();
#pragma unroll
    for (int it = 0; it < 2; ++it) {
        int g = t + 256 * it;
        int n = g >> 3, kg = (g & 7) * 8;
        u16x8 o;
#pragma unroll
        for (int e = 0; e < 8; ++e) o[e] = f2bf(Ws[kg + e][n]);
        *(u16x8 *)(WT + (size_t)(nt * 64 + n) * 512 + kt * 64 + kg) = o;
    }
}

// ---------------------------------------------------------------------------
// Projection GEMMs (bf16 MFMA), 128x128 tile, BK=64, 4 waves (2x2, 64x64).
// C = bf16act(Xbf @ WT^T + bias) -> qcat/kcat/vcat [bh][s][128].
// XCD-aware swizzle: each XCD owns a contiguous 16-m-tile chunk (2 MB A slice
// + 0.5 MB WT fit its private 4 MB L2).
// ---------------------------------------------------------------------------
__global__ void __launch_bounds__(256) mgemm0_k(Args P) {
    const int op = blockIdx.z;
    const int srcidx[6] = {0, 0, 1, 2, 2, 3};
    const unsigned short *Abf = P.xbf + (size_t)srcidx[op] * 8388608;
    const unsigned short *WT = P.wt + (size_t)op * 262144;
    const float *bias = P.bias[op];
    unsigned short *dstb; int doff, act;
    switch (op) {
        case 0: dstb = P.qcat; doff = 0;  act = 0; break;
        case 1: dstb = P.kcat; doff = 0;  act = 0; break;
        case 2: dstb = P.vcat; doff = 0;  act = 0; break;
        case 3: dstb = P.qcat; doff = 64; act = 1; break;
        case 4: dstb = P.kcat; doff = 64; act = 1; break;
        default:dstb = P.vcat; doff = 64; act = 2; break;
    }
    // XCD swizzle (dispatch idx % 8 == XCD; 512 blocks per op, 512%8==0)
    const int lin = blockIdx.y * 4 + blockIdx.x;       // 0..511
    const int xcd = lin & 7, idx = lin >> 3;           // idx 0..63
    const int m0 = (xcd * 16 + (idx >> 2)) * 128;
    const int n0 = (idx & 3) * 128;

    __shared__ unsigned short As[128][64];
    __shared__ unsigned short Bs[128][64];
    const int t = threadIdx.x;
    const int wid = t >> 6, lane = t & 63;
    const int wm = wid >> 1, wn = wid & 1;
    const int l16 = lane & 15, lq = lane >> 4;

    f32x4 acc[4][4];
#pragma unroll
    for (int i = 0; i < 4; ++i)
#pragma unroll
        for (int j = 0; j < 4; ++j) acc[i][j] = (f32x4)(0.f);

    for (int k0 = 0; k0 < 512; k0 += 64) {
        __syncthreads();
#pragma unroll
        for (int it = 0; it < 4; ++it) {
            int g = t + 256 * it;
            int r = g >> 3, cg = g & 7;
            bf16x8 av = *(const bf16x8 *)(Abf + (size_t)(m0 + r) * 512 + k0 + cg * 8);
            *(bf16x8 *)&As[r][(cg ^ (r & 7)) * 8] = av;
            bf16x8 bv = *(const bf16x8 *)(WT + (size_t)(n0 + r) * 512 + k0 + cg * 8);
            *(bf16x8 *)&Bs[r][(cg ^ (r & 7)) * 8] = bv;
        }
        __syncthreads();
#pragma unroll
        for (int kk = 0; kk < 2; ++kk) {
            bf16x8 a[4], b[4];
#pragma unroll
            for (int mf = 0; mf < 4; ++mf) {
                int r = wm * 64 + mf * 16 + l16;
                int cg = kk * 4 + lq;
                a[mf] = *(const bf16x8 *)&As[r][(cg ^ (r & 7)) * 8];
            }
#pragma unroll
            for (int nf = 0; nf < 4; ++nf) {
                int r = wn * 64 + nf * 16 + l16;
                int cg = kk * 4 + lq;
                b[nf] = *(const bf16x8 *)&Bs[r][(cg ^ (r & 7)) * 8];
            }
#pragma unroll
            for (int mf = 0; mf < 4; ++mf)
#pragma unroll
                for (int nf = 0; nf < 4; ++nf)
                    acc[mf][nf] = __builtin_amdgcn_mfma_f32_16x16x32_bf16(a[mf], b[nf], acc[mf][nf], 0, 0, 0);
        }
    }

#pragma unroll
    for (int mf = 0; mf < 4; ++mf) {
#pragma unroll
        for (int nf = 0; nf < 4; ++nf) {
#pragma unroll
            for (int r = 0; r < 4; ++r) {
                const int i = m0 + wm * 64 + mf * 16 + lq * 4 + r;
                const int j = n0 + wn * 64 + nf * 16 + l16;
                float v = acc[mf][nf][r] + bias[j];
                if (act == 1) {
                    float e = v > 0.f ? v + 1.f : expf(v);
                    v = sqrtf(fmaxf(e, 1e-24f));
                } else if (act == 2) {
                    v = v > 0.f ? v + 1.f : expf(v);
                }
                const int b_ = i >> 10, s_ = i & (SLEN - 1);
                const int h_ = j >> 6, d_ = j & (DH - 1);
                dstb[((size_t)(b_ * NH + h_) * SLEN + s_) * 128 + doff + d_] = f2bf(v);
            }
        }
    }
}

// ---------------------------------------------------------------------------
// Transpose vcat [bh][s][128] -> vcat_t [bh][d][1024]. grid (8, 128) x 256.
// ---------------------------------------------------------------------------
__global__ void __launch_bounds__(256) vtrans_k(Args P) {
    const int bh = blockIdx.y;
    const int s0 = blockIdx.x * 128;
    __shared__ unsigned short Ts[128][136];
    const unsigned short *src = P.vcat + (size_t)bh * SLEN * 128;
    unsigned short *dst = P.vcat_t + (size_t)bh * 128 * SLEN;
    const int t = threadIdx.x;
#pragma unroll
    for (int it = 0; it < 8; ++it) {
        int g = t + 256 * it;
        int s = g >> 4, dg = g & 15;
        *(u16x8 *)&Ts[s][dg * 8] = *(const u16x8 *)(src + (size_t)(s0 + s) * 128 + dg * 8);
    }
    __syncthreads();
#pragma unroll
    for (int it = 0; it < 8; ++it) {
        int g = t + 256 * it;
        int d = g >> 4, sg = g & 15;
        u16x8 o;
#pragma unroll
        for (int e = 0; e < 8; ++e) o[e] = Ts[sg * 8 + e][d];
        *(u16x8 *)(dst + (size_t)d * SLEN + s0 + sg * 8) = o;
    }
}

// ---------------------------------------------------------------------------
// Row sums from bf16 qcat/kcat (consistent with MFMA operand values).
// ---------------------------------------------------------------------------
__global__ void __launch_bounds__(256) rowsum_k(Args P) {
    const int t = threadIdx.x;
    const int wv = t >> 6, lane = t & 63;
    const long long row = (long long)blockIdx.x * 4 + wv;    // 0..262143
    const unsigned short *src = (row < BHROWS) ? P.qcat : P.kcat;
    const long long r = row & (BHROWS - 1);
    const unsigned short *p = src + r * 128;
    float a = bf2f(p[lane]), b = bf2f(p[64 + lane]);
    float v = a * a + b * b;
#pragma unroll
    for (int o = 32; o > 0; o >>= 1) v += __shfl_xor(v, o);
    if (lane == 0) P.sums[row] = v;
}

// ---------------------------------------------------------------------------
// Fused flash attention, 1024 threads = 16 waves.
// Round-10 changes (overlap the per-CU serial costs):
//  - T14 prefetch: next K/V tile global->reg issued right after the current
//    ds_write; HBM/L2 latency hides under the current tile's MFMA+exp.
//  - Probs writes interleaved into the PV loop (tile kt's 16 KB written right
//    after its PV MFMAs; T already known) -- no separate store-only phase.
//  - Causal-tail zeros + V[0] prefetch issued before the T-reduce (overlap).
// ---------------------------------------------------------------------------
__global__ void __launch_bounds__(1024, 4) flash_k(Args P) {
    const int bh = blockIdx.x;
    const int qt = 15 - (int)blockIdx.y;
    const int q0 = qt * 64;
    __shared__ unsigned short Ep[64][1024];    // 128 KB
    __shared__ unsigned short Ks[64][128];     // 16 KB (phase 2 aliases as V)
    __shared__ float Tred[4][64];              // per-quarter row partials
    __shared__ float Tsh[64];                  // 1/T per row (0 for s==0)
    unsigned short (*Vt)[64] = reinterpret_cast<unsigned short (*)[64]>(&Ks[0][0]);

    const int t = threadIdx.x;
    const int w = t >> 6, lane = t & 63;
    const int l16 = lane & 15, lq = lane >> 4;
    const int mg = w >> 2, q4 = w & 3;

    const unsigned short *qc = P.qcat + (size_t)bh * SLEN * 128;
    const unsigned short *kc = P.kcat + (size_t)bh * SLEN * 128;
    const float *qsum = P.sums + (size_t)bh * SLEN;
    const float *ksum = P.sums + BHROWS + (size_t)bh * SLEN;
    float *pout = P.probs + ((size_t)bh * SLEN + q0) * SLEN;

    // Q fragments: row = q0 + mg*16 + l16, k-group kk*4+lq (covers 128 dims).
    const unsigned short *qrow = qc + (size_t)(q0 + mg * 16 + l16) * 128;
    bf16x8 qfr[4];
#pragma unroll
    for (int kk = 0; kk < 4; ++kk) qfr[kk] = *(const bf16x8 *)(qrow + (kk * 4 + lq) * 8);
    float qs[4];
#pragma unroll
    for (int r = 0; r < 4; ++r) qs[r] = qsum[q0 + mg * 16 + lq * 4 + r];

    const int nkt = qt + 1;
    float tpart[4] = {0.f, 0.f, 0.f, 0.f};    // fp32 row-total partials

    // ---- Phase 1: masked exp(scores) into the panel, K prefetched ----
    const int sr = t >> 4, sg = t & 15;        // K staging: row, 16B group
    const int rK = q4 * 16 + l16;
    bf16x8 kreg = *(const bf16x8 *)(kc + (size_t)sr * 128 + sg * 8);
    float ksreg = ksum[rK];

    for (int kt = 0; kt < nkt; ++kt) {
        __syncthreads();                       // Ks free (prev reads done)
        *(bf16x8 *)&Ks[sr][(sg ^ (sr & 7)) * 8] = kreg;
        if (kt + 1 < nkt)
            kreg = *(const bf16x8 *)(kc + (size_t)((kt + 1) * 64 + sr) * 128 + sg * 8);
        __syncthreads();                       // Ks ready

        const float ksv = ksreg;
        if (kt + 1 < nkt) ksreg = ksum[(kt + 1) * 64 + rK];

        f32x4 acc = (f32x4)(0.f);
#pragma unroll
        for (int kk = 0; kk < 4; ++kk) {
            bf16x8 b = *(const bf16x8 *)&Ks[rK][((kk * 4 + lq) ^ (rK & 7)) * 8];
            acc = __builtin_amdgcn_mfma_f32_16x16x32_bf16(qfr[kk], b, acc, 0, 0, 0);
        }
        const int j = kt * 64 + rK;
#pragma unroll
        for (int r = 0; r < 4; ++r) {
            const int row = mg * 16 + lq * 4 + r;
            const int i = q0 + row;
            float sv = (2.f * acc[r] - qs[r] - ksv) * 0.125f;
            float e = (j <= i) ? __expf(sv) : 0.f;
            tpart[r] += e;
            Ep[row][(((j >> 3) ^ (row & 7)) << 3) | (j & 7)] = f2bf(e);
        }
    }

    // ---- V[0] prefetch + causal-tail zeros (overlap with the reduce) ----
    const int vr = t >> 3, vg = t & 7;         // V staging: d-row, 16B group
    const unsigned short *vtg = P.vcat_t + (size_t)bh * 128 * SLEN;
    bf16x8 vreg = *(const bf16x8 *)(vtg + (size_t)vr * SLEN + vg * 8);
    {
        const int zrow = t >> 4;
        f32x4 z = (f32x4)(0.f);
        for (int c4 = nkt * 16 + (t & 15); c4 < 256; c4 += 16)
            *(f32x4 *)(pout + (size_t)zrow * SLEN + c4 * 4) = z;
    }

    // ---- Row totals: reduce over the 16-lane group, combine 4 quarters ----
#pragma unroll
    for (int o = 1; o < 16; o <<= 1)
#pragma unroll
        for (int r = 0; r < 4; ++r) tpart[r] += __shfl_xor(tpart[r], o);
    if (l16 == 0) {
#pragma unroll
        for (int r = 0; r < 4; ++r) Tred[q4][mg * 16 + lq * 4 + r] = tpart[r];
    }
    __syncthreads();
    if (t < 64) {
        const int i = q0 + t;
        const float T = Tred[0][t] + Tred[1][t] + Tred[2][t] + Tred[3][t];
        Tsh[t] = (i == 0) ? 0.f : (1.f / T);   // zero_pad row 0
    }
    __syncthreads();

    // ---- Phase 2: PV (V prefetched) + interleaved normalized probs writes --
    const int cov = q4 >> 1;
    f32x4 pacc[2];
    pacc[0] = (f32x4)(0.f); pacc[1] = (f32x4)(0.f);
    for (int kt = 0; kt < nkt; ++kt) {
        __syncthreads();                       // Vt free
        *(bf16x8 *)&Vt[vr][(vg ^ (vr & 7)) * 8] = vreg;
        if (kt + 1 < nkt)
            vreg = *(const bf16x8 *)(vtg + (size_t)vr * SLEN + (kt + 1) * 64 + vg * 8);
        __syncthreads();                       // Vt ready

#pragma unroll
        for (int kk = 0; kk < 2; ++kk) {
            const int row = mg * 16 + l16;
            const int gg = (kt * 8) + kk * 4 + lq;
            bf16x8 af = *(const bf16x8 *)&Ep[row][((gg ^ (row & 7)) << 3)];
            if (cov) {                          // cov operand: elementwise square
                u16x8 u = (u16x8)af, sq;
#pragma unroll
                for (int e = 0; e < 8; ++e) {
                    float f = bf2f(u[e]);
                    sq[e] = f2bf(f * f);
                }
                af = (bf16x8)sq;
            }
#pragma unroll
            for (int nf = 0; nf < 2; ++nf) {
                const int d = q4 * 32 + nf * 16 + l16;
                bf16x8 bf = *(const bf16x8 *)&Vt[d][((kk * 4 + lq) ^ (d & 7)) * 8];
                pacc[nf] = __builtin_amdgcn_mfma_f32_16x16x32_bf16(af, bf, pacc[nf], 0, 0, 0);
            }
        }

        // normalized probs write for tile kt (mask only on the diagonal tile)
        {
            const int prow = t >> 4, slot = t & 15;
            const int col = kt * 64 + slot * 4;
            const int g = col >> 3, o4 = (slot & 1) * 4;
            u16x8 v = *(const u16x8 *)&Ep[prow][((g ^ (prow & 7)) << 3)];
            const float inv = Tsh[prow];
            f32x4 ov;
            if (kt == qt) {
                const int i = q0 + prow;
#pragma unroll
                for (int e = 0; e < 4; ++e)
                    ov[e] = (col + e <= i) ? bf2f(v[o4 + e]) * inv : 0.f;
            } else {
#pragma unroll
                for (int e = 0; e < 4; ++e)
                    ov[e] = bf2f(v[o4 + e]) * inv;
            }
            *(f32x4 *)(pout + (size_t)prow * SLEN + col) = ov;
        }
    }

    unsigned short *dst = cov ? P.ctxc : P.ctxm;
    const int b_ = bh >> 3, h_ = bh & 7;
#pragma unroll
    for (int nf = 0; nf < 2; ++nf) {
#pragma unroll
        for (int r = 0; r < 4; ++r) {
            const int row = mg * 16 + lq * 4 + r;
            const int s_ = q0 + row;
            const float inv = Tsh[row];
            const float scale = cov ? inv * inv : inv;    // /T or /T^2 (0 for row 0)
            dst[((size_t)b_ * SLEN + s_) * HDIM + h_ * 64 + (q4 & 1) * 32 + nf * 16 + l16] =
                f2bf(pacc[nf][r] * scale);
        }
    }
}

// ---------------------------------------------------------------------------
// Fused output GEMM + bias + residual + LayerNorm.
// out = LN(ctx @ WT^T + bias + resid).  Tile 64(M) x 512(N, full row), BK=64.
// 512 threads = 8 waves (2 m-bands x 4 n-bands); each wave 32x128 output.
// grid (256 m-tiles, 2 ops).
// ---------------------------------------------------------------------------
__global__ void __launch_bounds__(512, 4) mgemm_ln_k(Args P) {
    const int op = blockIdx.y;
    const unsigned short *Abf = op ? P.ctxc : P.ctxm;
    const unsigned short *WT = P.wt + (size_t)(6 + op) * 262144;
    const float *bias = P.bias[6 + op];
    const float *resid = op ? P.xc : P.xm;
    float *out = op ? P.out_c : P.out_m;
    const int m0 = blockIdx.x * 64;

    __shared__ unsigned short As[64][64];      // 8 KB
    __shared__ unsigned short Bs[512][64];     // 64 KB
    __shared__ float Red[64][4][2];            // 2 KB

    const int t = threadIdx.x;
    const int w = t >> 6, lane = t & 63;
    const int wm = w >> 2, wn = w & 3;         // 2 x 4 waves
    const int l16 = lane & 15, lq = lane >> 4;

    f32x4 acc[2][8];
#pragma unroll
    for (int mf = 0; mf < 2; ++mf)
#pragma unroll
        for (int nf = 0; nf < 8; ++nf) acc[mf][nf] = (f32x4)(0.f);

    for (int k0 = 0; k0 < 512; k0 += 64) {
        __syncthreads();
        {   // stage A: 64 rows x 8 groups = 512 slots, 1/thread
            int r = t >> 3, cg = t & 7;
            *(bf16x8 *)&As[r][(cg ^ (r & 7)) * 8] =
                *(const bf16x8 *)(Abf + (size_t)(m0 + r) * 512 + k0 + cg * 8);
        }
#pragma unroll
        for (int it = 0; it < 8; ++it) {       // stage B: 512 rows x 8 groups
            int g = t + 512 * it;
            int r = g >> 3, cg = g & 7;
            *(bf16x8 *)&Bs[r][(cg ^ (r & 7)) * 8] =
                *(const bf16x8 *)(WT + (size_t)r * 512 + k0 + cg * 8);
        }
        __syncthreads();
#pragma unroll
        for (int kk = 0; kk < 2; ++kk) {
            bf16x8 a[2];
#pragma unroll
            for (int mf = 0; mf < 2; ++mf) {
                int r = wm * 32 + mf * 16 + l16;
                a[mf] = *(const bf16x8 *)&As[r][((kk * 4 + lq) ^ (r & 7)) * 8];
            }
#pragma unroll
            for (int nf = 0; nf < 8; ++nf) {
                int rn = wn * 128 + nf * 16 + l16;
                bf16x8 b = *(const bf16x8 *)&Bs[rn][((kk * 4 + lq) ^ (rn & 7)) * 8];
#pragma unroll
                for (int mf = 0; mf < 2; ++mf)
                    acc[mf][nf] = __builtin_amdgcn_mfma_f32_16x16x32_bf16(a[mf], b, acc[mf][nf], 0, 0, 0);
            }
        }
    }

    // epilogue: bias + resid accumulated in place; LN partials per (mf,r)
    float bv[8];
#pragma unroll
    for (int nf = 0; nf < 8; ++nf) bv[nf] = bias[wn * 128 + nf * 16 + l16];

    float s0[2][4], s1[2][4];
#pragma unroll
    for (int mf = 0; mf < 2; ++mf)
#pragma unroll
        for (int r = 0; r < 4; ++r) { s0[mf][r] = 0.f; s1[mf][r] = 0.f; }

#pragma unroll
    for (int mf = 0; mf < 2; ++mf) {
#pragma unroll
        for (int r = 0; r < 4; ++r) {
            const int i = m0 + wm * 32 + mf * 16 + lq * 4 + r;
            const float *rrow = resid + (size_t)i * HDIM + wn * 128 + l16;
#pragma unroll
            for (int nf = 0; nf < 8; ++nf) {
                float x = acc[mf][nf][r] + bv[nf] + rrow[nf * 16];
                acc[mf][nf][r] = x;
                s0[mf][r] += x;
                s1[mf][r] += x * x;
            }
        }
    }
#pragma unroll
    for (int o = 1; o < 16; o <<= 1)
#pragma unroll
        for (int mf = 0; mf < 2; ++mf)
#pragma unroll
            for (int r = 0; r < 4; ++r) {
                s0[mf][r] += __shfl_xor(s0[mf][r], o);
                s1[mf][r] += __shfl_xor(s1[mf][r], o);
            }
    if (l16 == 0) {
#pragma unroll
        for (int mf = 0; mf < 2; ++mf)
#pragma unroll
            for (int r = 0; r < 4; ++r) {
                const int row = wm * 32 + mf * 16 + lq * 4 + r;
                Red[row][wn][0] = s0[mf][r];
                Red[row][wn][1] = s1[mf][r];
            }
    }
    __syncthreads();

    float lnw[8], lnb[8];
#pragma unroll
    for (int nf = 0; nf < 8; ++nf) {
        const int j = wn * 128 + nf * 16 + l16;
        lnw[nf] = P.ln_w[j]; lnb[nf] = P.ln_b[j];
    }
#pragma unroll
    for (int mf = 0; mf < 2; ++mf) {
#pragma unroll
        for (int r = 0; r < 4; ++r) {
            const int row = wm * 32 + mf * 16 + lq * 4 + r;
            const int i = m0 + row;
            const float S  = Red[row][0][0] + Red[row][1][0] + Red[row][2][0] + Red[row][3][0];
            const float SS = Red[row][0][1] + Red[row][1][1] + Red[row][2][1] + Red[row][3][1];
            const float mean = S * (1.f / 512.f);
            const float var = SS * (1.f / 512.f) - mean * mean;
            const float inv = 1.f / sqrtf(var + 1e-12f);
            float *orow = out + (size_t)i * HDIM + wn * 128 + l16;
#pragma unroll
            for (int nf = 0; nf < 8; ++nf)
                orow[nf * 16] = lnw[nf] * ((acc[mf][nf][r] - mean) * inv) + lnb[nf];
        }
    }
}

// ---------------------------------------------------------------------------
extern "C" void kernel_launch(void *const *d_in, const int *in_sizes, int n_in,
                              void *d_out, int out_size, void *d_ws, size_t ws_size,
                              hipStream_t stream) {
    (void)in_sizes; (void)n_in; (void)out_size; (void)ws_size;
    Args P;
    P.xm  = (const float *)d_in[0];
    P.xrm = (const float *)d_in[1];
    P.xc  = (const float *)d_in[2];
    P.xrc = (const float *)d_in[3];
    // d_in[4] = attn_mask: exactly where(causal,0,-1e4); the -1e4 branch
    // underflows to an exact 0 probability, reproduced by causal handling.
    for (int i = 0; i < 8; ++i) {
        P.w[i]    = (const float *)d_in[5 + 2 * i];
        P.bias[i] = (const float *)d_in[6 + 2 * i];
    }
    P.ln_w = (const float *)d_in[21];
    P.ln_b = (const float *)d_in[22];

    char *ws = (char *)d_ws;
    P.xbf    = (unsigned short *)(ws);
    P.vcat_t = (unsigned short *)(ws);                 // alias xbf[0..2) (dead)
    P.ctxm   = (unsigned short *)(ws + 33554432);      // alias xbf[2..3) (dead)
    P.ctxc   = (unsigned short *)(ws + 50331648);      // alias xbf[3..4) (dead)
    P.wt     = (unsigned short *)(ws + 67108864);
    P.sums   = (float *)(ws + 71303168);
    P.qcat   = (unsigned short *)(ws + 72351744);      // live through flash_k
    P.kcat   = (unsigned short *)(ws + 105906176);
    P.vcat   = (unsigned short *)(ws + 139460608);

    P.out_m = (float *)d_out;
    P.out_c = (float *)d_out + 8388608;
    P.probs = (float *)d_out + 16777216;

    cvt_inputs_k<<<dim3(4096, 4), dim3(256), 0, stream>>>(P);
    wtrans_k<<<dim3(64, 8), dim3(256), 0, stream>>>(P);
    mgemm0_k<<<dim3(4, 128, 6), dim3(256), 0, stream>>>(P);
    vtrans_k<<<dim3(8, 128), dim3(256), 0, stream>>>(P);
    rowsum_k<<<dim3(65536), dim3(256), 0, stream>>>(P);
    flash_k<<<dim3(128, 16), dim3(1024), 0, stream>>>(P);
    mgemm_ln_k<<<dim3(256, 2), dim3(512), 0, stream>>>(P);
}